// Round 6
// baseline (475.675 us; speedup 1.0000x reference)
//
#include <hip/hip_runtime.h>
#include <hip/hip_bf16.h>
#include <stdint.h>

typedef __bf16 bf16_t;
typedef __bf16 bf16x4 __attribute__((ext_vector_type(4)));
typedef __bf16 bf16x8 __attribute__((ext_vector_type(8)));
typedef float f32x4 __attribute__((ext_vector_type(4)));
typedef float f32x16 __attribute__((ext_vector_type(16)));

static_assert(sizeof(bf16x8) == 16, "bf16x8 must be 16B");

#define MFMA_BF16(a, b, c) __builtin_amdgcn_mfma_f32_16x16x32_bf16((a), (b), (c), 0, 0, 0)
// 32x32x16 bf16 MFMA: A[row=lane&31][k=(lane>>5)*8+i], B[k][col=lane&31],
// C/D: col=lane&31, row=(reg&3)+8*(reg>>2)+4*(lane>>5)
#define MFMA32(a, b, c) __builtin_amdgcn_mfma_f32_32x32x16_bf16((a), (b), (c), 0, 0, 0)

typedef const __attribute__((address_space(1))) void* gas_ptr;
typedef __attribute__((address_space(3))) void* las_ptr;

__device__ __forceinline__ void gload_lds16(const void* g, void* l) {
  __builtin_amdgcn_global_load_lds((gas_ptr)g, (las_ptr)l, 16, 0, 0);
}

#define ORDER_FENCE() asm volatile("" ::: "memory")
#define NEG_BIG (-1.0e30f)

// ---------------------------------------------------------------------------
// fp32 -> bf16 convert, all three inputs in one launch.
// ---------------------------------------------------------------------------
__global__ __launch_bounds__(256) void cvt3_kernel(
    const float* __restrict__ x, const float* __restrict__ wq,
    const float* __restrict__ wp, bf16_t* __restrict__ xb,
    bf16_t* __restrict__ wqb, bf16_t* __restrict__ wpb) {
  const int i = (blockIdx.x * 256 + threadIdx.x) * 4;
  const float* src;
  bf16_t* dst;
  int off;
  if (i < 8388608) {
    src = x; dst = xb; off = 0;
  } else if (i < 9175040) {
    src = wq; dst = wqb; off = 8388608;
  } else {
    src = wp; dst = wpb; off = 9175040;
  }
  const f32x4 v = *(const f32x4*)(src + (i - off));
  bf16x4 o;
  o[0] = (bf16_t)v[0];
  o[1] = (bf16_t)v[1];
  o[2] = (bf16_t)v[2];
  o[3] = (bf16_t)v[3];
  *(bf16x4*)(dst + (i - off)) = o;
}

// ---------------------------------------------------------------------------
// GEMM (m97 structure): D[m][n] = sum_k A[m][k] * Bw[n][k]   (unchanged)
// ---------------------------------------------------------------------------
template <int MODE>
__global__ __launch_bounds__(256, 2) void gemm_bt_kernel(
    const bf16_t* __restrict__ A, const bf16_t* __restrict__ Bw,
    bf16_t* __restrict__ o_q, bf16_t* __restrict__ o_k, bf16_t* __restrict__ o_vT,
    float* __restrict__ o_f) {
  constexpr int K = 512;
  __shared__ bf16_t As[128 * 32];
  __shared__ bf16_t Bs[128 * 32];

  const int tid = threadIdx.x;
  const int lane = tid & 63;
  const int wid = tid >> 6;
  const int quad = lane >> 4;
  const int l15 = lane & 15;
  const int wm = wid >> 1;
  const int wn = wid & 1;

  const int mt = blockIdx.x & 127;
  const int nt = blockIdx.x >> 7;
  const int row0 = mt * 128;
  const int col0 = nt * 128;

  f32x4 acc[4][4] = {};

  for (int kt = 0; kt < K; kt += 32) {
    __syncthreads();
#pragma unroll
    for (int rnd = 0; rnd < 2; rnd++) {
      const int e = (rnd * 256 + tid) * 8;
      const int r = e >> 5;
      const int c = e & 31;
      gload_lds16(A + (size_t)(row0 + r) * K + kt + c, As + e);
      gload_lds16(Bw + (size_t)(col0 + r) * K + kt + c, Bs + e);
    }
    __syncthreads();

    bf16x8 af[4], bfr[4];
#pragma unroll
    for (int i = 0; i < 4; i++)
      af[i] = *(const bf16x8*)(As + (wm * 64 + i * 16 + l15) * 32 + quad * 8);
#pragma unroll
    for (int i = 0; i < 4; i++)
      bfr[i] = *(const bf16x8*)(Bs + (wn * 64 + i * 16 + l15) * 32 + quad * 8);
#pragma unroll
    for (int mi = 0; mi < 4; mi++)
#pragma unroll
      for (int ni = 0; ni < 4; ni++)
        acc[mi][ni] = MFMA_BF16(af[mi], bfr[ni], acc[mi][ni]);
  }

#pragma unroll
  for (int mi = 0; mi < 4; mi++) {
    const int row = row0 + wm * 64 + mi * 16 + quad * 4;
#pragma unroll
    for (int ni = 0; ni < 4; ni++) {
      const int col = col0 + wn * 64 + ni * 16 + l15;
#pragma unroll
      for (int r = 0; r < 4; r++) {
        const int rr = row + r;
        if constexpr (MODE == 0) {
          const bf16_t bv = (bf16_t)acc[mi][ni][r];
          if (col < 512) {
            o_q[(size_t)rr * 512 + col] = bv;
          } else if (col < 1024) {
            o_k[(size_t)rr * 512 + (col - 512)] = bv;
          } else {
            const int bb = rr >> 12;
            const int t = rr & 4095;
            o_vT[((size_t)bb * 512 + (col - 1024)) * 4096 + t] = bv;
          }
        } else {
          o_f[(size_t)rr * 512 + col] = acc[mi][ni][r];
        }
      }
    }
  }
}

// ---------------------------------------------------------------------------
// Attention stage 1 — 32x32x16 MFMA, counted-vmcnt pipeline, COALESCED staging.
// Block (b,s,c): 64 q, 512 kv, 512 d. Grid = 1152. Waves: wq=wid&1, wk=wid>>1.
// All staged slices have 128-B contiguous (within-line permuted) runs:
//   K-slice u (u=0..15, dg=u>>1, kh=u&1): [256 kv][8 units] of K rows,
//     unit pc holds d-chunk (pc^(kv&7)) of [dg*64,+64).
//   Q-slice dg (into PL[dg&1], 8 KB): [64 q][8 units] of d-chunks likewise.
//   V-slice v (kc=v>>1, dh=v&1): [256 d][8 units] of kv-chunks of [kc*64,+64).
// Per iter: {vmcnt(8); barrier; MFMAs (setprio); lgkm(0); barrier; stage u+2}.
// Softmax: per-lane row (q = wq*32+l31), shfl_xor(32) + cross-wk LDS exchange
// (SMX/SLR alias PL[1] — dead region at that point). P exchanged via PL dbuf
// (64q x 64kv chunks), produced one chunk ahead by its owner wave.
// partO native layout, dense 256-B wave stores:
//   flat = bid*32768 + (((wq*2+dh)*2+wk)*4+dtl)*1024 + (u*2+h)*128 + l31*4 + j
//   q = wq*32+u*8+h*4+j ; d = dh*256+wk*128+dtl*32+l31.
// ---------------------------------------------------------------------------
__global__ __launch_bounds__(256, 2) void attn_part_kernel(
    const bf16_t* __restrict__ q, const bf16_t* __restrict__ k,
    const bf16_t* __restrict__ vT, bf16_t* __restrict__ partO,
    float2* __restrict__ stats) {
  __shared__ bf16_t SB[2][16384];  // 2 x 32 KB slice double buffer
  __shared__ bf16_t PL[2][4096];   // 2 x 8 KB: Q slices (ph1) / P chunks (ph3)
  float* SMX = (float*)&PL[1][0];    // 512 B, [wq*2+wk][l31]
  float* SLR = (float*)&PL[1][256];  // 512 B

  const int tid = threadIdx.x;
  const int lane = tid & 63;
  const int wid = tid >> 6;
  const int h = lane >> 5;
  const int l31 = lane & 31;
  const int wq = wid & 1;
  const int wk = wid >> 1;

  const int bid = blockIdx.x;
  const int b = bid & 3;
  const int w = bid >> 2;  // 0..287
  int g = 0;
  while (w >= 4 * (g + 1) * (g + 2)) g++;
  const int rem = w - 4 * g * (g + 1);
  const int i = rem / (g + 1);
  const int c = rem - i * (g + 1);
  const int s = 8 * g + i;

  const int kv0 = c * 512;
  const int qmaxw = s * 64 + wq * 32 + 31;                  // wave's max q-row
  const int NKC = min(8, ((s * 64 + 63 - kv0) >> 6) + 1);   // live 64-kv chunks

  const float scale = 0.044194173824159216f;  // 1/sqrt(512)
  const bf16_t* kbase = k + ((size_t)b * 4096 + kv0) * 512;
  const bf16_t* vbase = vT + ((size_t)b * 512) * 4096 + kv0;
  const bf16_t* qgbase = q + ((size_t)(b * 4096 + s * 64)) * 512;

  // K-slice u: 8 loads/thread, 8 lanes per 128-B line.
  auto stageK = [&](int u, int buf) {
    const int dg = u >> 1, kh = u & 1;
#pragma unroll
    for (int rnd = 0; rnd < 8; rnd++) {
      const int ch = rnd * 256 + tid;
      const int kl = ch >> 3, pc = ch & 7;
      gload_lds16(kbase + (size_t)(kh * 256 + kl) * 512 + dg * 64 +
                      ((pc ^ (kl & 7)) * 8),
                  &SB[buf][ch * 8]);
    }
  };
  // V-slice v: 8 loads/thread, 8 lanes per 128-B line.
  auto stageV = [&](int v, int buf) {
    const int kc = v >> 1, dh = v & 1;
#pragma unroll
    for (int rnd = 0; rnd < 8; rnd++) {
      const int ch = rnd * 256 + tid;
      const int dl = ch >> 3, pc = ch & 7;
      gload_lds16(vbase + (size_t)(dh * 256 + dl) * 4096 + kc * 64 +
                      ((pc ^ (dl & 7)) * 8),
                  &SB[buf][ch * 8]);
    }
  };
  // Q-slice dg into PL[dg&1]: 2 loads/thread, coalesced.
  auto stageQ = [&](int dg) {
#pragma unroll
    for (int rnd = 0; rnd < 2; rnd++) {
      const int ch = rnd * 256 + tid;
      const int ql = ch >> 3, pc = ch & 7;
      gload_lds16(qgbase + (size_t)ql * 512 + dg * 64 + ((pc ^ (ql & 7)) * 8),
                  &PL[dg & 1][ch * 8]);
    }
  };

  // ---- prologue (order pinned: Q0, K0, K1) --------------------------------
  stageQ(0);
  ORDER_FENCE();
  stageK(0, 0);
  ORDER_FENCE();
  stageK(1, 1);
  ORDER_FENCE();

  // ---- Phase 1: S^T accumulate (8 tiles/wave: t = kh*4+mt) ----------------
  f32x16 Sacc[8] = {};
  int cur = 0;
#pragma unroll
  for (int u = 0; u < 16; u++) {
    const int dg = u >> 1, kh = u & 1;
    asm volatile("s_waitcnt vmcnt(8)" ::: "memory");
    __builtin_amdgcn_sched_barrier(0);
    __builtin_amdgcn_s_barrier();
    const char* sb = (const char*)&SB[cur][0];
    const char* qlds = (const char*)&PL[dg & 1][0];
    __builtin_amdgcn_s_setprio(1);
    bf16x8 qf[4];
#pragma unroll
    for (int ks = 0; ks < 4; ks++)
      qf[ks] = *(const bf16x8*)(qlds + (wq * 32 + l31) * 128 +
                                (((ks * 2 + h) ^ (l31 & 7)) << 4));
#pragma unroll
    for (int mt = 0; mt < 4; mt++) {
      if (kv0 + kh * 256 + wk * 128 + mt * 32 <= qmaxw) {  // wave-uniform
#pragma unroll
        for (int ks = 0; ks < 4; ks++) {
          const bf16x8 kf = *(const bf16x8*)(
              sb + (wk * 128 + mt * 32 + l31) * 128 +
              (((ks * 2 + h) ^ (l31 & 7)) << 4));
          Sacc[kh * 4 + mt] = MFMA32(kf, qf[ks], Sacc[kh * 4 + mt]);
        }
      }
    }
    __builtin_amdgcn_s_setprio(0);
    asm volatile("s_waitcnt lgkmcnt(0)" ::: "memory");
    __builtin_amdgcn_sched_barrier(0);
    __builtin_amdgcn_s_barrier();
    if ((u & 1) && u < 15) {
      stageQ(dg + 1);
      ORDER_FENCE();
    }
    if (u < 14)
      stageK(u + 2, cur);
    else
      stageV(u - 14, cur);  // V slices 0,1 (always live)
    cur ^= 1;
  }

  // ---- Phase 2: softmax (lane = q-row wq*32+l31) --------------------------
  const int qr = s * 64 + wq * 32 + l31;
  float mx = NEG_BIG;
#pragma unroll
  for (int t = 0; t < 8; t++) {
    const int kvb = kv0 + (t >> 2) * 256 + wk * 128 + (t & 3) * 32;
    if (kvb <= qmaxw) {
#pragma unroll
      for (int r = 0; r < 16; r++) {
        const int kvg = kvb + (r & 3) + 8 * (r >> 2) + 4 * h;
        if (kvg <= qr) mx = fmaxf(mx, Sacc[t][r]);
      }
    }
  }
  mx = fmaxf(mx, __shfl_xor(mx, 32));
  if (lane < 32) SMX[(wq * 2 + wk) * 32 + l31] = mx;
  asm volatile("s_waitcnt lgkmcnt(0)" ::: "memory");
  __builtin_amdgcn_sched_barrier(0);
  __builtin_amdgcn_s_barrier();
  const float M = fmaxf(SMX[(wq * 2) * 32 + l31], SMX[(wq * 2 + 1) * 32 + l31]);

  float lrow = 0.0f;
  bf16x4 pb[8][4] = {};
#pragma unroll
  for (int t = 0; t < 8; t++) {
    const int kvb = kv0 + (t >> 2) * 256 + wk * 128 + (t & 3) * 32;
    if (kvb <= qmaxw) {
#pragma unroll
      for (int u = 0; u < 4; u++) {
        bf16x4 pv = {};
#pragma unroll
        for (int j = 0; j < 4; j++) {
          const int kvg = kvb + u * 8 + 4 * h + j;
          float p = 0.0f;
          if (kvg <= qr) p = __expf((Sacc[t][u * 4 + j] - M) * scale);
          pv[j] = (bf16_t)p;
          lrow += p;
        }
        pb[t][u] = pv;
      }
    }
  }
  lrow += __shfl_xor(lrow, 32);
  if (lane < 32) SLR[(wq * 2 + wk) * 32 + l31] = lrow;
  asm volatile("s_waitcnt lgkmcnt(0)" ::: "memory");
  __builtin_amdgcn_sched_barrier(0);
  __builtin_amdgcn_s_barrier();
  const float L = SLR[(wq * 2) * 32 + l31] + SLR[(wq * 2 + 1) * 32 + l31];
  if (wk == 0 && lane < 32)
    stats[((size_t)w * 4 + b) * 64 + wq * 32 + l31] = make_float2(M * scale, L);

  // write P chunk kc into PL[kc&1] (caller: wave with wk == (kc>>1)&1)
  auto pwrite = [&](int kc) {
    const int kh = kc >> 2;
    char* pl = (char*)&PL[kc & 1][0];
#pragma unroll
    for (int mtp = 0; mtp < 2; mtp++) {
      const int t = kh * 4 + (kc & 1) * 2 + mtp;
#pragma unroll
      for (int u = 0; u < 4; u++) {
        *(bf16x4*)(pl + (wq * 32 + l31) * 128 +
                   (((mtp * 4 + u) ^ (l31 & 7)) << 4) + h * 8) = pb[t][u];
      }
    }
  };
  if (wk == 0) pwrite(0);
  asm volatile("s_waitcnt lgkmcnt(0)" ::: "memory");
  __builtin_amdgcn_sched_barrier(0);
  __builtin_amdgcn_s_barrier();

  // ---- Phase 3: O = P.V (slices alternate dh; Oacc[dh*4+dtl]) -------------
  f32x16 Oacc[8] = {};
#pragma unroll
  for (int v = 0; v < 16; v++) {
    if (v < 2 * NKC) {  // block-uniform
      const int kc = v >> 1, dh = v & 1;
      if (v == 2 * NKC - 1)
        asm volatile("s_waitcnt vmcnt(0)" ::: "memory");
      else
        asm volatile("s_waitcnt vmcnt(8)" ::: "memory");
      __builtin_amdgcn_sched_barrier(0);
      __builtin_amdgcn_s_barrier();
      if (kv0 + kc * 64 <= qmaxw) {  // wave-uniform live
        const char* sb = (const char*)&SB[cur][0];
        const char* pl = (const char*)&PL[kc & 1][0];
        __builtin_amdgcn_s_setprio(1);
#pragma unroll
        for (int ks = 0; ks < 4; ks++) {
          const bf16x8 pA = *(const bf16x8*)(
              pl + (wq * 32 + l31) * 128 + (((ks * 2 + h) ^ (l31 & 7)) << 4));
#pragma unroll
          for (int dtl = 0; dtl < 4; dtl++) {
            const bf16x8 vB = *(const bf16x8*)(
                sb + ((wk * 4 + dtl) * 32 + l31) * 128 +
                (((ks * 2 + h) ^ (l31 & 7)) << 4));
            Oacc[dh * 4 + dtl] = MFMA32(pA, vB, Oacc[dh * 4 + dtl]);
          }
        }
        __builtin_amdgcn_s_setprio(0);
      }
      if ((v & 1) && (kc + 1) < NKC && wk == (((kc + 1) >> 1) & 1))
        pwrite(kc + 1);
      asm volatile("s_waitcnt lgkmcnt(0)" ::: "memory");
      __builtin_amdgcn_sched_barrier(0);
      __builtin_amdgcn_s_barrier();
      if (v + 2 < 2 * NKC) stageV(v + 2, cur);
      cur ^= 1;
    }
  }

  // ---- epilogue: dense native-layout partO stores (256 B per wave-store) --
  bf16_t* pb0 = partO + (size_t)bid * 32768;
#pragma unroll
  for (int t = 0; t < 8; t++) {
    const int dh = t >> 2, dtl = t & 3;
    bf16_t* base =
        pb0 + (size_t)((((wq * 2 + dh) * 2 + wk) * 4 + dtl)) * 1024;
#pragma unroll
    for (int u = 0; u < 4; u++) {
      bf16x4 ov;
#pragma unroll
      for (int j = 0; j < 4; j++) ov[j] = (bf16_t)Oacc[t][u * 4 + j];
      *(bf16x4*)(base + (u * 2 + h) * 128 + l31 * 4) = ov;
    }
  }
}

// ---------------------------------------------------------------------------
// Stage 2: combine chunk partials per (b, s). Coalesced native-layout reads,
// register accumulate, XOR-swizzled 64-KB LDS transpose, coalesced writes.
// ---------------------------------------------------------------------------
__global__ __launch_bounds__(256) void attn_combine_kernel(
    const bf16_t* __restrict__ partO, const float2* __restrict__ stats,
    bf16_t* __restrict__ o) {
  const int b = blockIdx.x & 3;
  const int s = blockIdx.x >> 2;
  const int g = s >> 3;
  const int nc = g + 1;
  const int w0 = 4 * g * (g + 1) + (s & 7) * (g + 1);

  __shared__ float wgt[8][64];
  __shared__ float linv[64];
  __shared__ bf16_t TB[64 * 512];  // 64 KB transpose bounce

  const int tid = threadIdx.x;
  if (tid < 64) {
    float mc[8], lc[8];
    float M = NEG_BIG;
    for (int cc = 0; cc < nc; cc++) {
      const float2 ml = stats[((size_t)(w0 + cc) * 4 + b) * 64 + tid];
      mc[cc] = ml.x;
      lc[cc] = ml.y;
      M = fmaxf(M, ml.x);
    }
    float L = 0.0f;
    for (int cc = 0; cc < nc; cc++) {
      const float wv = __expf(mc[cc] - M);
      wgt[cc][tid] = wv;
      L += wv * lc[cc];
    }
    linv[tid] = (L > 0.0f) ? 1.0f / L : 0.0f;
  }
  __syncthreads();

  // group G (bf16x4): l31=G&31; u=(G>>6)&3; h=(G>>5)&1; dtl=(G>>8)&3;
  // wk=(G>>10)&1; dh=(G>>11)&1; wq=G>>12. q=wq*32+u*8+h*4+j; d=dh*256+wk*128+dtl*32+l31.
#pragma unroll
  for (int sw = 0; sw < 32; sw++) {
    const int G = sw * 256 + tid;
    const int l31 = G & 31;
    const int hh = (G >> 5) & 1;
    const int u = (G >> 6) & 3;
    const int dtl = (G >> 8) & 3;
    const int wkk = (G >> 10) & 1;
    const int dhh = (G >> 11) & 1;
    const int wqq = G >> 12;
    const int q0 = wqq * 32 + u * 8 + hh * 4;
    const int d = dhh * 256 + wkk * 128 + dtl * 32 + l31;

    f32x4 acc = {};
    for (int cc = 0; cc < nc; cc++) {
      const int bidc = ((w0 + cc) << 2) | b;
      const bf16x4 p =
          *(const bf16x4*)(partO + (size_t)bidc * 32768 + (size_t)G * 4);
      const f32x4 wv = *(const f32x4*)(&wgt[cc][q0]);
#pragma unroll
      for (int e = 0; e < 4; e++) acc[e] += wv[e] * (float)p[e];
    }
    const f32x4 li = *(const f32x4*)(&linv[q0]);
#pragma unroll
    for (int j = 0; j < 4; j++) {
      const int qq = q0 + j;
      *(bf16_t*)((char*)TB + qq * 1024 + ((d * 2) ^ ((qq & 7) << 4))) =
          (bf16_t)(acc[j] * li[j]);
    }
  }
  __syncthreads();

  // coalesced read + store: thread = (row q, 128-d quarter)
  const int row = tid >> 2;
  const int dq = (tid & 3) * 128;
  bf16_t* orow = o + ((size_t)(b * 4096 + s * 64 + row)) * 512 + dq;
#pragma unroll
  for (int jj = 0; jj < 16; jj++) {
    const int byte = row * 1024 + (((dq + jj * 8) * 2) ^ ((row & 7) << 4));
    *(bf16x8*)(orow + jj * 8) = *(const bf16x8*)((const char*)TB + byte);
  }
}

// ---------------------------------------------------------------------------
extern "C" void kernel_launch(void* const* d_in, const int* in_sizes, int n_in,
                              void* d_out, int out_size, void* d_ws, size_t ws_size,
                              hipStream_t stream) {
  const float* x_f = (const float*)d_in[0];   // [4,4096,512] fp32
  const float* wq_f = (const float*)d_in[1];  // [1536,512]   fp32
  const float* wp_f = (const float*)d_in[2];  // [512,512]    fp32
  float* out = (float*)d_out;                 // [4,4096,512] fp32

  bf16_t* xb = (bf16_t*)d_ws;                      // 16 MB (attn output)
  bf16_t* wqb = xb + (size_t)16384 * 512;          // 1.5 MB
  bf16_t* wpb = wqb + (size_t)1536 * 512;          // 0.5 MB
  bf16_t* q = wpb + (size_t)512 * 512;             // 16 MB
  bf16_t* kk = q + (size_t)16384 * 512;            // 16 MB
  bf16_t* vT = kk + (size_t)16384 * 512;           // 16 MB
  bf16_t* partO = vT + (size_t)16384 * 512;        // 75.5 MB
  float2* stats = (float2*)(partO + (size_t)1152 * 32768);  // 0.6 MB

  cvt3_kernel<<<9216, 256, 0, stream>>>(x_f, wq_f, wp_f, xb, wqb, wpb);
  gemm_bt_kernel<0><<<128 * 12, 256, 0, stream>>>(xb, wqb, q, kk, vT, nullptr);
  attn_part_kernel<<<1152, 256, 0, stream>>>(q, kk, vT, partO, stats);
  attn_combine_kernel<<<256, 256, 0, stream>>>(partO, stats, xb);
  gemm_bt_kernel<1><<<128 * 4, 256, 0, stream>>>(xb, wpb, nullptr, nullptr, nullptr, out);
}

// Round 7
// 472.127 us; speedup vs baseline: 1.0075x; 1.0075x over previous
//
#include <hip/hip_runtime.h>
#include <hip/hip_bf16.h>
#include <stdint.h>

typedef __bf16 bf16_t;
typedef __bf16 bf16x4 __attribute__((ext_vector_type(4)));
typedef __bf16 bf16x8 __attribute__((ext_vector_type(8)));
typedef float f32x4 __attribute__((ext_vector_type(4)));
typedef float f32x16 __attribute__((ext_vector_type(16)));

static_assert(sizeof(bf16x8) == 16, "bf16x8 must be 16B");

#define MFMA_BF16(a, b, c) __builtin_amdgcn_mfma_f32_16x16x32_bf16((a), (b), (c), 0, 0, 0)
// 32x32x16 bf16 MFMA: A[row=lane&31][k=(lane>>5)*8+i], B[k][col=lane&31],
// C/D: col=lane&31, row=(reg&3)+8*(reg>>2)+4*(lane>>5)
#define MFMA32(a, b, c) __builtin_amdgcn_mfma_f32_32x32x16_bf16((a), (b), (c), 0, 0, 0)

typedef const __attribute__((address_space(1))) void* gas_ptr;
typedef __attribute__((address_space(3))) void* las_ptr;

__device__ __forceinline__ void gload_lds16(const void* g, void* l) {
  __builtin_amdgcn_global_load_lds((gas_ptr)g, (las_ptr)l, 16, 0, 0);
}

#define ORDER_FENCE() asm volatile("" ::: "memory")
#define NEG_BIG (-1.0e30f)

// ---------------------------------------------------------------------------
// fp32 -> bf16 convert, all three inputs in one launch.
// ---------------------------------------------------------------------------
__global__ __launch_bounds__(256) void cvt3_kernel(
    const float* __restrict__ x, const float* __restrict__ wq,
    const float* __restrict__ wp, bf16_t* __restrict__ xb,
    bf16_t* __restrict__ wqb, bf16_t* __restrict__ wpb) {
  const int i = (blockIdx.x * 256 + threadIdx.x) * 4;
  const float* src;
  bf16_t* dst;
  int off;
  if (i < 8388608) {
    src = x; dst = xb; off = 0;
  } else if (i < 9175040) {
    src = wq; dst = wqb; off = 8388608;
  } else {
    src = wp; dst = wpb; off = 9175040;
  }
  const f32x4 v = *(const f32x4*)(src + (i - off));
  bf16x4 o;
  o[0] = (bf16_t)v[0];
  o[1] = (bf16_t)v[1];
  o[2] = (bf16_t)v[2];
  o[3] = (bf16_t)v[3];
  *(bf16x4*)(dst + (i - off)) = o;
}

// ---------------------------------------------------------------------------
// GEMM (m97 structure): D[m][n] = sum_k A[m][k] * Bw[n][k]
// XCD-swizzled blockIdx (grid divisible by 8) for L2 locality.
// ---------------------------------------------------------------------------
template <int MODE>
__global__ __launch_bounds__(256, 2) void gemm_bt_kernel(
    const bf16_t* __restrict__ A, const bf16_t* __restrict__ Bw,
    bf16_t* __restrict__ o_q, bf16_t* __restrict__ o_k, bf16_t* __restrict__ o_vT,
    float* __restrict__ o_f) {
  constexpr int K = 512;
  __shared__ bf16_t As[128 * 32];
  __shared__ bf16_t Bs[128 * 32];

  const int tid = threadIdx.x;
  const int lane = tid & 63;
  const int wid = tid >> 6;
  const int quad = lane >> 4;
  const int l15 = lane & 15;
  const int wm = wid >> 1;
  const int wn = wid & 1;

  // bijective XCD swizzle: consecutive per-XCD ids share nt (B panel hot)
  const int rb = (blockIdx.x & 7) * ((int)gridDim.x >> 3) + (blockIdx.x >> 3);
  const int mt = rb & 127;
  const int nt = rb >> 7;
  const int row0 = mt * 128;
  const int col0 = nt * 128;

  f32x4 acc[4][4] = {};

  for (int kt = 0; kt < K; kt += 32) {
    __syncthreads();
#pragma unroll
    for (int rnd = 0; rnd < 2; rnd++) {
      const int e = (rnd * 256 + tid) * 8;
      const int r = e >> 5;
      const int c = e & 31;
      gload_lds16(A + (size_t)(row0 + r) * K + kt + c, As + e);
      gload_lds16(Bw + (size_t)(col0 + r) * K + kt + c, Bs + e);
    }
    __syncthreads();

    bf16x8 af[4], bfr[4];
#pragma unroll
    for (int i = 0; i < 4; i++)
      af[i] = *(const bf16x8*)(As + (wm * 64 + i * 16 + l15) * 32 + quad * 8);
#pragma unroll
    for (int i = 0; i < 4; i++)
      bfr[i] = *(const bf16x8*)(Bs + (wn * 64 + i * 16 + l15) * 32 + quad * 8);
#pragma unroll
    for (int mi = 0; mi < 4; mi++)
#pragma unroll
      for (int ni = 0; ni < 4; ni++)
        acc[mi][ni] = MFMA_BF16(af[mi], bfr[ni], acc[mi][ni]);
  }

#pragma unroll
  for (int mi = 0; mi < 4; mi++) {
    const int row = row0 + wm * 64 + mi * 16 + quad * 4;
#pragma unroll
    for (int ni = 0; ni < 4; ni++) {
      const int col = col0 + wn * 64 + ni * 16 + l15;
#pragma unroll
      for (int r = 0; r < 4; r++) {
        const int rr = row + r;
        if constexpr (MODE == 0) {
          const bf16_t bv = (bf16_t)acc[mi][ni][r];
          if (col < 512) {
            o_q[(size_t)rr * 512 + col] = bv;
          } else if (col < 1024) {
            o_k[(size_t)rr * 512 + (col - 512)] = bv;
          } else {
            const int bb = rr >> 12;
            const int t = rr & 4095;
            o_vT[((size_t)bb * 512 + (col - 1024)) * 4096 + t] = bv;
          }
        } else {
          o_f[(size_t)rr * 512 + col] = acc[mi][ni][r];
        }
      }
    }
  }
}

// ---------------------------------------------------------------------------
// Attention stage 1 — 32x32x16 MFMA, counted-vmcnt pipeline, coalesced
// staging, REUSE-AWARE XCD PLACEMENT.
// Blocks sharing the K/V chunk (b, c) are pinned to one XCD (bid&7 round-
// robin): XCD = b*2 + (c in {0,2,4} ? 0 : 1); 144 blocks per XCD. All
// concurrent blocks on an XCD share the same 1-MB K/V chunk -> L2-resident,
// d-slice revisits become L2 hits (this was the ~5 TB/s fabric wall).
// partO/stats keep the legacy (w, b) indexing -> combine unchanged.
// Body identical to round 6.
// ---------------------------------------------------------------------------
__global__ __launch_bounds__(256, 2) void attn_part_kernel(
    const bf16_t* __restrict__ q, const bf16_t* __restrict__ k,
    const bf16_t* __restrict__ vT, bf16_t* __restrict__ partO,
    float2* __restrict__ stats) {
  __shared__ bf16_t SB[2][16384];  // 2 x 32 KB slice double buffer
  __shared__ bf16_t PL[2][4096];   // 2 x 8 KB: Q slices (ph1) / P chunks (ph3)
  float* SMX = (float*)&PL[1][0];    // 512 B, [wq*2+wk][l31]
  float* SLR = (float*)&PL[1][256];  // 512 B

  const int tid = threadIdx.x;
  const int lane = tid & 63;
  const int wid = tid >> 6;
  const int h = lane >> 5;
  const int l31 = lane & 31;
  const int wq = wid & 1;
  const int wk = wid >> 1;

  // ---- reuse-aware decode: bid -> (b, s, c); groups (b,c) pinned per XCD --
  const int x = blockIdx.x & 7;   // XCD (round-robin)
  const int n = blockIdx.x >> 3;  // 0..143 within XCD
  const int b = x >> 1;
  int c, i;
  if ((x & 1) == 0) {             // c in {0,2,4}: sizes 64,48,32
    if (n < 64)       { c = 0; i = n; }
    else if (n < 112) { c = 2; i = n - 64; }
    else              { c = 4; i = n - 112; }
  } else {                        // c in {1,3,5,6,7}: sizes 56,40,24,16,8
    if (n < 56)       { c = 1; i = n; }
    else if (n < 96)  { c = 3; i = n - 56; }
    else if (n < 120) { c = 5; i = n - 96; }
    else if (n < 136) { c = 6; i = n - 120; }
    else              { c = 7; i = n - 136; }
  }
  const int s = 8 * c + i;        // strips using chunk c are s >= 8c
  const int g = s >> 3;
  const int w = 4 * g * (g + 1) + (s & 7) * (g + 1) + c;  // legacy index
  const int obid = (w << 2) | b;                          // legacy partO slot

  const int kv0 = c * 512;
  const int qmaxw = s * 64 + wq * 32 + 31;                  // wave's max q-row
  const int NKC = min(8, ((s * 64 + 63 - kv0) >> 6) + 1);   // live 64-kv chunks

  const float scale = 0.044194173824159216f;  // 1/sqrt(512)
  const bf16_t* kbase = k + ((size_t)b * 4096 + kv0) * 512;
  const bf16_t* vbase = vT + ((size_t)b * 512) * 4096 + kv0;
  const bf16_t* qgbase = q + ((size_t)(b * 4096 + s * 64)) * 512;

  // K-slice u: 8 loads/thread, 8 lanes per 128-B line.
  auto stageK = [&](int u, int buf) {
    const int dg = u >> 1, kh = u & 1;
#pragma unroll
    for (int rnd = 0; rnd < 8; rnd++) {
      const int ch = rnd * 256 + tid;
      const int kl = ch >> 3, pc = ch & 7;
      gload_lds16(kbase + (size_t)(kh * 256 + kl) * 512 + dg * 64 +
                      ((pc ^ (kl & 7)) * 8),
                  &SB[buf][ch * 8]);
    }
  };
  // V-slice v: 8 loads/thread, 8 lanes per 128-B line.
  auto stageV = [&](int v, int buf) {
    const int kc = v >> 1, dh = v & 1;
#pragma unroll
    for (int rnd = 0; rnd < 8; rnd++) {
      const int ch = rnd * 256 + tid;
      const int dl = ch >> 3, pc = ch & 7;
      gload_lds16(vbase + (size_t)(dh * 256 + dl) * 4096 + kc * 64 +
                      ((pc ^ (dl & 7)) * 8),
                  &SB[buf][ch * 8]);
    }
  };
  // Q-slice dg into PL[dg&1]: 2 loads/thread, coalesced.
  auto stageQ = [&](int dg) {
#pragma unroll
    for (int rnd = 0; rnd < 2; rnd++) {
      const int ch = rnd * 256 + tid;
      const int ql = ch >> 3, pc = ch & 7;
      gload_lds16(qgbase + (size_t)ql * 512 + dg * 64 + ((pc ^ (ql & 7)) * 8),
                  &PL[dg & 1][ch * 8]);
    }
  };

  // ---- prologue (order pinned: Q0, K0, K1) --------------------------------
  stageQ(0);
  ORDER_FENCE();
  stageK(0, 0);
  ORDER_FENCE();
  stageK(1, 1);
  ORDER_FENCE();

  // ---- Phase 1: S^T accumulate (8 tiles/wave: t = kh*4+mt) ----------------
  f32x16 Sacc[8] = {};
  int cur = 0;
#pragma unroll
  for (int u = 0; u < 16; u++) {
    const int dg = u >> 1, kh = u & 1;
    asm volatile("s_waitcnt vmcnt(8)" ::: "memory");
    __builtin_amdgcn_sched_barrier(0);
    __builtin_amdgcn_s_barrier();
    const char* sb = (const char*)&SB[cur][0];
    const char* qlds = (const char*)&PL[dg & 1][0];
    __builtin_amdgcn_s_setprio(1);
    bf16x8 qf[4];
#pragma unroll
    for (int ks = 0; ks < 4; ks++)
      qf[ks] = *(const bf16x8*)(qlds + (wq * 32 + l31) * 128 +
                                (((ks * 2 + h) ^ (l31 & 7)) << 4));
#pragma unroll
    for (int mt = 0; mt < 4; mt++) {
      if (kv0 + kh * 256 + wk * 128 + mt * 32 <= qmaxw) {  // wave-uniform
#pragma unroll
        for (int ks = 0; ks < 4; ks++) {
          const bf16x8 kf = *(const bf16x8*)(
              sb + (wk * 128 + mt * 32 + l31) * 128 +
              (((ks * 2 + h) ^ (l31 & 7)) << 4));
          Sacc[kh * 4 + mt] = MFMA32(kf, qf[ks], Sacc[kh * 4 + mt]);
        }
      }
    }
    __builtin_amdgcn_s_setprio(0);
    asm volatile("s_waitcnt lgkmcnt(0)" ::: "memory");
    __builtin_amdgcn_sched_barrier(0);
    __builtin_amdgcn_s_barrier();
    if ((u & 1) && u < 15) {
      stageQ(dg + 1);
      ORDER_FENCE();
    }
    if (u < 14)
      stageK(u + 2, cur);
    else
      stageV(u - 14, cur);  // V slices 0,1 (always live)
    cur ^= 1;
  }

  // ---- Phase 2: softmax (lane = q-row wq*32+l31) --------------------------
  const int qr = s * 64 + wq * 32 + l31;
  float mx = NEG_BIG;
#pragma unroll
  for (int t = 0; t < 8; t++) {
    const int kvb = kv0 + (t >> 2) * 256 + wk * 128 + (t & 3) * 32;
    if (kvb <= qmaxw) {
#pragma unroll
      for (int r = 0; r < 16; r++) {
        const int kvg = kvb + (r & 3) + 8 * (r >> 2) + 4 * h;
        if (kvg <= qr) mx = fmaxf(mx, Sacc[t][r]);
      }
    }
  }
  mx = fmaxf(mx, __shfl_xor(mx, 32));
  if (lane < 32) SMX[(wq * 2 + wk) * 32 + l31] = mx;
  asm volatile("s_waitcnt lgkmcnt(0)" ::: "memory");
  __builtin_amdgcn_sched_barrier(0);
  __builtin_amdgcn_s_barrier();
  const float M = fmaxf(SMX[(wq * 2) * 32 + l31], SMX[(wq * 2 + 1) * 32 + l31]);

  float lrow = 0.0f;
  bf16x4 pb[8][4] = {};
#pragma unroll
  for (int t = 0; t < 8; t++) {
    const int kvb = kv0 + (t >> 2) * 256 + wk * 128 + (t & 3) * 32;
    if (kvb <= qmaxw) {
#pragma unroll
      for (int u = 0; u < 4; u++) {
        bf16x4 pv = {};
#pragma unroll
        for (int j = 0; j < 4; j++) {
          const int kvg = kvb + u * 8 + 4 * h + j;
          float p = 0.0f;
          if (kvg <= qr) p = __expf((Sacc[t][u * 4 + j] - M) * scale);
          pv[j] = (bf16_t)p;
          lrow += p;
        }
        pb[t][u] = pv;
      }
    }
  }
  lrow += __shfl_xor(lrow, 32);
  if (lane < 32) SLR[(wq * 2 + wk) * 32 + l31] = lrow;
  asm volatile("s_waitcnt lgkmcnt(0)" ::: "memory");
  __builtin_amdgcn_sched_barrier(0);
  __builtin_amdgcn_s_barrier();
  const float L = SLR[(wq * 2) * 32 + l31] + SLR[(wq * 2 + 1) * 32 + l31];
  if (wk == 0 && lane < 32)
    stats[((size_t)w * 4 + b) * 64 + wq * 32 + l31] = make_float2(M * scale, L);

  // write P chunk kc into PL[kc&1] (caller: wave with wk == (kc>>1)&1)
  auto pwrite = [&](int kc) {
    const int kh = kc >> 2;
    char* pl = (char*)&PL[kc & 1][0];
#pragma unroll
    for (int mtp = 0; mtp < 2; mtp++) {
      const int t = kh * 4 + (kc & 1) * 2 + mtp;
#pragma unroll
      for (int u = 0; u < 4; u++) {
        *(bf16x4*)(pl + (wq * 32 + l31) * 128 +
                   (((mtp * 4 + u) ^ (l31 & 7)) << 4) + h * 8) = pb[t][u];
      }
    }
  };
  if (wk == 0) pwrite(0);
  asm volatile("s_waitcnt lgkmcnt(0)" ::: "memory");
  __builtin_amdgcn_sched_barrier(0);
  __builtin_amdgcn_s_barrier();

  // ---- Phase 3: O = P.V (slices alternate dh; Oacc[dh*4+dtl]) -------------
  f32x16 Oacc[8] = {};
#pragma unroll
  for (int v = 0; v < 16; v++) {
    if (v < 2 * NKC) {  // block-uniform
      const int kc = v >> 1, dh = v & 1;
      if (v == 2 * NKC - 1)
        asm volatile("s_waitcnt vmcnt(0)" ::: "memory");
      else
        asm volatile("s_waitcnt vmcnt(8)" ::: "memory");
      __builtin_amdgcn_sched_barrier(0);
      __builtin_amdgcn_s_barrier();
      if (kv0 + kc * 64 <= qmaxw) {  // wave-uniform live
        const char* sb = (const char*)&SB[cur][0];
        const char* pl = (const char*)&PL[kc & 1][0];
        __builtin_amdgcn_s_setprio(1);
#pragma unroll
        for (int ks = 0; ks < 4; ks++) {
          const bf16x8 pA = *(const bf16x8*)(
              pl + (wq * 32 + l31) * 128 + (((ks * 2 + h) ^ (l31 & 7)) << 4));
#pragma unroll
          for (int dtl = 0; dtl < 4; dtl++) {
            const bf16x8 vB = *(const bf16x8*)(
                sb + ((wk * 4 + dtl) * 32 + l31) * 128 +
                (((ks * 2 + h) ^ (l31 & 7)) << 4));
            Oacc[dh * 4 + dtl] = MFMA32(pA, vB, Oacc[dh * 4 + dtl]);
          }
        }
        __builtin_amdgcn_s_setprio(0);
      }
      if ((v & 1) && (kc + 1) < NKC && wk == (((kc + 1) >> 1) & 1))
        pwrite(kc + 1);
      asm volatile("s_waitcnt lgkmcnt(0)" ::: "memory");
      __builtin_amdgcn_sched_barrier(0);
      __builtin_amdgcn_s_barrier();
      if (v + 2 < 2 * NKC) stageV(v + 2, cur);
      cur ^= 1;
    }
  }

  // ---- epilogue: dense native-layout partO stores (legacy obid slot) ------
  bf16_t* pb0 = partO + (size_t)obid * 32768;
#pragma unroll
  for (int t = 0; t < 8; t++) {
    const int dh = t >> 2, dtl = t & 3;
    bf16_t* base =
        pb0 + (size_t)((((wq * 2 + dh) * 2 + wk) * 4 + dtl)) * 1024;
#pragma unroll
    for (int u = 0; u < 4; u++) {
      bf16x4 ov;
#pragma unroll
      for (int j = 0; j < 4; j++) ov[j] = (bf16_t)Oacc[t][u * 4 + j];
      *(bf16x4*)(base + (u * 2 + h) * 128 + l31 * 4) = ov;
    }
  }
}

// ---------------------------------------------------------------------------
// Stage 2: combine chunk partials per (b, s). Coalesced native-layout reads,
// register accumulate, XOR-swizzled 64-KB LDS transpose, coalesced writes.
// (unchanged — partO/stats keep legacy indexing)
// ---------------------------------------------------------------------------
__global__ __launch_bounds__(256) void attn_combine_kernel(
    const bf16_t* __restrict__ partO, const float2* __restrict__ stats,
    bf16_t* __restrict__ o) {
  const int b = blockIdx.x & 3;
  const int s = blockIdx.x >> 2;
  const int g = s >> 3;
  const int nc = g + 1;
  const int w0 = 4 * g * (g + 1) + (s & 7) * (g + 1);

  __shared__ float wgt[8][64];
  __shared__ float linv[64];
  __shared__ bf16_t TB[64 * 512];  // 64 KB transpose bounce

  const int tid = threadIdx.x;
  if (tid < 64) {
    float mc[8], lc[8];
    float M = NEG_BIG;
    for (int cc = 0; cc < nc; cc++) {
      const float2 ml = stats[((size_t)(w0 + cc) * 4 + b) * 64 + tid];
      mc[cc] = ml.x;
      lc[cc] = ml.y;
      M = fmaxf(M, ml.x);
    }
    float L = 0.0f;
    for (int cc = 0; cc < nc; cc++) {
      const float wv = __expf(mc[cc] - M);
      wgt[cc][tid] = wv;
      L += wv * lc[cc];
    }
    linv[tid] = (L > 0.0f) ? 1.0f / L : 0.0f;
  }
  __syncthreads();

  // group G (bf16x4): l31=G&31; u=(G>>6)&3; h=(G>>5)&1; dtl=(G>>8)&3;
  // wk=(G>>10)&1; dh=(G>>11)&1; wq=G>>12. q=wq*32+u*8+h*4+j; d=dh*256+wk*128+dtl*32+l31.
#pragma unroll
  for (int sw = 0; sw < 32; sw++) {
    const int G = sw * 256 + tid;
    const int l31 = G & 31;
    const int hh = (G >> 5) & 1;
    const int u = (G >> 6) & 3;
    const int dtl = (G >> 8) & 3;
    const int wkk = (G >> 10) & 1;
    const int dhh = (G >> 11) & 1;
    const int wqq = G >> 12;
    const int q0 = wqq * 32 + u * 8 + hh * 4;
    const int d = dhh * 256 + wkk * 128 + dtl * 32 + l31;

    f32x4 acc = {};
    for (int cc = 0; cc < nc; cc++) {
      const int bidc = ((w0 + cc) << 2) | b;
      const bf16x4 p =
          *(const bf16x4*)(partO + (size_t)bidc * 32768 + (size_t)G * 4);
      const f32x4 wv = *(const f32x4*)(&wgt[cc][q0]);
#pragma unroll
      for (int e = 0; e < 4; e++) acc[e] += wv[e] * (float)p[e];
    }
    const f32x4 li = *(const f32x4*)(&linv[q0]);
#pragma unroll
    for (int j = 0; j < 4; j++) {
      const int qq = q0 + j;
      *(bf16_t*)((char*)TB + qq * 1024 + ((d * 2) ^ ((qq & 7) << 4))) =
          (bf16_t)(acc[j] * li[j]);
    }
  }
  __syncthreads();

  // coalesced read + store: thread = (row q, 128-d quarter)
  const int row = tid >> 2;
  const int dq = (tid & 3) * 128;
  bf16_t* orow = o + ((size_t)(b * 4096 + s * 64 + row)) * 512 + dq;
#pragma unroll
  for (int jj = 0; jj < 16; jj++) {
    const int byte = row * 1024 + (((dq + jj * 8) * 2) ^ ((row & 7) << 4));
    *(bf16x8*)(orow + jj * 8) = *(const bf16x8*)((const char*)TB + byte);
  }
}

// ---------------------------------------------------------------------------
extern "C" void kernel_launch(void* const* d_in, const int* in_sizes, int n_in,
                              void* d_out, int out_size, void* d_ws, size_t ws_size,
                              hipStream_t stream) {
  const float* x_f = (const float*)d_in[0];   // [4,4096,512] fp32
  const float* wq_f = (const float*)d_in[1];  // [1536,512]   fp32
  const float* wp_f = (const float*)d_in[2];  // [512,512]    fp32
  float* out = (float*)d_out;                 // [4,4096,512] fp32

  bf16_t* xb = (bf16_t*)d_ws;                      // 16 MB (attn output)
  bf16_t* wqb = xb + (size_t)16384 * 512;          // 1.5 MB
  bf16_t* wpb = wqb + (size_t)1536 * 512;          // 0.5 MB
  bf16_t* q = wpb + (size_t)512 * 512;             // 16 MB
  bf16_t* kk = q + (size_t)16384 * 512;            // 16 MB
  bf16_t* vT = kk + (size_t)16384 * 512;           // 16 MB
  bf16_t* partO = vT + (size_t)16384 * 512;        // 75.5 MB
  float2* stats = (float2*)(partO + (size_t)1152 * 32768);  // 0.6 MB

  cvt3_kernel<<<9216, 256, 0, stream>>>(x_f, wq_f, wp_f, xb, wqb, wpb);
  gemm_bt_kernel<0><<<128 * 12, 256, 0, stream>>>(xb, wqb, q, kk, vT, nullptr);
  attn_part_kernel<<<1152, 256, 0, stream>>>(q, kk, vT, partO, stats);
  attn_combine_kernel<<<256, 256, 0, stream>>>(partO, stats, xb);
  gemm_bt_kernel<1><<<128 * 4, 256, 0, stream>>>(xb, wpb, nullptr, nullptr, nullptr, out);
}

// Round 8
// 432.732 us; speedup vs baseline: 1.0992x; 1.0910x over previous
//
#include <hip/hip_runtime.h>
#include <hip/hip_bf16.h>
#include <stdint.h>

typedef __bf16 bf16_t;
typedef __bf16 bf16x4 __attribute__((ext_vector_type(4)));
typedef __bf16 bf16x8 __attribute__((ext_vector_type(8)));
typedef short s16x4 __attribute__((ext_vector_type(4)));
typedef float f32x4 __attribute__((ext_vector_type(4)));

static_assert(sizeof(bf16x8) == 16, "bf16x8 must be 16B");

#define MFMA_BF16(a, b, c) __builtin_amdgcn_mfma_f32_16x16x32_bf16((a), (b), (c), 0, 0, 0)

// 16x16x16 bf16 MFMA (A[m=l15][k=quad*4+i], B[k=quad*4+i][n=l15],
// C/D row=quad*4+r col=l15)
__device__ __forceinline__ f32x4 mfma16(bf16x4 a, bf16x4 b, f32x4 c) {
#if __has_builtin(__builtin_amdgcn_mfma_f32_16x16x16bf16_1k)
  union { bf16x4 h; s16x4 s; } ua, ub;
  ua.h = a;
  ub.h = b;
  return __builtin_amdgcn_mfma_f32_16x16x16bf16_1k(ua.s, ub.s, c, 0, 0, 0);
#else
  f32x4 d = c;
  asm volatile("v_mfma_f32_16x16x16_bf16 %0, %1, %2, %0" : "+v"(d) : "v"(a), "v"(b));
  return d;
#endif
}

typedef const __attribute__((address_space(1))) void* gas_ptr;
typedef __attribute__((address_space(3))) void* las_ptr;

__device__ __forceinline__ void gload_lds16(const void* g, void* l) {
  __builtin_amdgcn_global_load_lds((gas_ptr)g, (las_ptr)l, 16, 0, 0);
}

// compile-time memory-op ordering fence (pins global_load_lds issue order)
#define ORDER_FENCE() asm volatile("" ::: "memory")

#define NEG_BIG (-1.0e30f)

// ---------------------------------------------------------------------------
// fp32 -> bf16 convert, all three inputs in one launch.
// ---------------------------------------------------------------------------
__global__ __launch_bounds__(256) void cvt3_kernel(
    const float* __restrict__ x, const float* __restrict__ wq,
    const float* __restrict__ wp, bf16_t* __restrict__ xb,
    bf16_t* __restrict__ wqb, bf16_t* __restrict__ wpb) {
  const int i = (blockIdx.x * 256 + threadIdx.x) * 4;
  const float* src;
  bf16_t* dst;
  int off;
  if (i < 8388608) {
    src = x; dst = xb; off = 0;
  } else if (i < 9175040) {
    src = wq; dst = wqb; off = 8388608;
  } else {
    src = wp; dst = wpb; off = 9175040;
  }
  const f32x4 v = *(const f32x4*)(src + (i - off));
  bf16x4 o;
  o[0] = (bf16_t)v[0];
  o[1] = (bf16_t)v[1];
  o[2] = (bf16_t)v[2];
  o[3] = (bf16_t)v[3];
  *(bf16x4*)(dst + (i - off)) = o;
}

// ---------------------------------------------------------------------------
// GEMM (m97 structure): D[m][n] = sum_k A[m][k] * Bw[n][k]
// ---------------------------------------------------------------------------
template <int MODE>
__global__ __launch_bounds__(256, 2) void gemm_bt_kernel(
    const bf16_t* __restrict__ A, const bf16_t* __restrict__ Bw,
    bf16_t* __restrict__ o_q, bf16_t* __restrict__ o_k, bf16_t* __restrict__ o_vT,
    float* __restrict__ o_f) {
  constexpr int K = 512;
  __shared__ bf16_t As[128 * 32];
  __shared__ bf16_t Bs[128 * 32];

  const int tid = threadIdx.x;
  const int lane = tid & 63;
  const int wid = tid >> 6;
  const int quad = lane >> 4;
  const int l15 = lane & 15;
  const int wm = wid >> 1;
  const int wn = wid & 1;

  const int mt = blockIdx.x & 127;
  const int nt = blockIdx.x >> 7;
  const int row0 = mt * 128;
  const int col0 = nt * 128;

  f32x4 acc[4][4] = {};

  for (int kt = 0; kt < K; kt += 32) {
    __syncthreads();
#pragma unroll
    for (int rnd = 0; rnd < 2; rnd++) {
      const int e = (rnd * 256 + tid) * 8;
      const int r = e >> 5;
      const int c = e & 31;
      gload_lds16(A + (size_t)(row0 + r) * K + kt + c, As + e);
      gload_lds16(Bw + (size_t)(col0 + r) * K + kt + c, Bs + e);
    }
    __syncthreads();

    bf16x8 af[4], bfr[4];
#pragma unroll
    for (int i = 0; i < 4; i++)
      af[i] = *(const bf16x8*)(As + (wm * 64 + i * 16 + l15) * 32 + quad * 8);
#pragma unroll
    for (int i = 0; i < 4; i++)
      bfr[i] = *(const bf16x8*)(Bs + (wn * 64 + i * 16 + l15) * 32 + quad * 8);
#pragma unroll
    for (int mi = 0; mi < 4; mi++)
#pragma unroll
      for (int ni = 0; ni < 4; ni++)
        acc[mi][ni] = MFMA_BF16(af[mi], bfr[ni], acc[mi][ni]);
  }

#pragma unroll
  for (int mi = 0; mi < 4; mi++) {
    const int row = row0 + wm * 64 + mi * 16 + quad * 4;
#pragma unroll
    for (int ni = 0; ni < 4; ni++) {
      const int col = col0 + wn * 64 + ni * 16 + l15;
#pragma unroll
      for (int r = 0; r < 4; r++) {
        const int rr = row + r;
        if constexpr (MODE == 0) {
          const bf16_t bv = (bf16_t)acc[mi][ni][r];
          if (col < 512) {
            o_q[(size_t)rr * 512 + col] = bv;
          } else if (col < 1024) {
            o_k[(size_t)rr * 512 + (col - 512)] = bv;
          } else {
            const int bb = rr >> 12;
            const int t = rr & 4095;
            o_vT[((size_t)bb * 512 + (col - 1024)) * 4096 + t] = bv;
          }
        } else {
          o_f[(size_t)rr * 512 + col] = acc[mi][ni][r];
        }
      }
    }
  }
}

// ---------------------------------------------------------------------------
// Split-KV flash attention stage 1 — counted-vmcnt raw-barrier pipeline
// (exact R4 body = best measured 206 us) + reuse-aware XCD placement:
// blocks sharing the K/V chunk (b, c) are pinned to one XCD (bid&7 round-
// robin): XCD = b*2 + (c in {0,2,4} ? 0 : 1); 144 blocks per XCD -> the
// 1-MB K/V chunk stays L2-resident (R7 A/B: FETCH 234->104 MB).
// setprio REMOVED (m190: hurts barrier-lockstep structures).
// partO/stats keep legacy (w, b) indexing -> combine unchanged.
// ---------------------------------------------------------------------------
__global__ __launch_bounds__(256, 2) void attn_part_kernel(
    const bf16_t* __restrict__ q, const bf16_t* __restrict__ k,
    const bf16_t* __restrict__ vT, bf16_t* __restrict__ partO,
    float2* __restrict__ stats) {
  __shared__ bf16_t SB[2][16384];  // 2 x 32 KB double buffer

  const int tid = threadIdx.x;
  const int lane = tid & 63;
  const int wid = tid >> 6;
  const int quad = lane >> 4;
  const int l15 = lane & 15;

  // ---- reuse-aware decode: bid -> (b, s, c); groups (b,c) pinned per XCD --
  const int x = blockIdx.x & 7;   // XCD (round-robin)
  const int n = blockIdx.x >> 3;  // 0..143 within XCD
  const int b = x >> 1;
  int c, i;
  if ((x & 1) == 0) {             // c in {0,2,4}: sizes 64,48,32
    if (n < 64)       { c = 0; i = n; }
    else if (n < 112) { c = 2; i = n - 64; }
    else              { c = 4; i = n - 112; }
  } else {                        // c in {1,3,5,6,7}: sizes 56,40,24,16,8
    if (n < 56)       { c = 1; i = n; }
    else if (n < 96)  { c = 3; i = n - 56; }
    else if (n < 120) { c = 5; i = n - 96; }
    else if (n < 136) { c = 6; i = n - 120; }
    else              { c = 7; i = n - 136; }
  }
  const int s = 8 * c + i;        // valid strips for chunk c are s >= 8c
  const int g = s >> 3;
  const int w = 4 * g * (g + 1) + (s & 7) * (g + 1) + c;  // legacy index
  const int obid = (w << 2) | b;                          // legacy partO slot

  const int t0w = s * 64 + wid * 16;  // this wave's q rows
  const int kv0 = c * 512;
  const int mmax = min(31, (t0w + 15 - kv0) >> 4);         // wave-uniform
  const int kvtmax = mmax >> 2;                            // wave-uniform
  const int mmax_blk = min(31, (s * 64 + 63 - kv0) >> 4);  // block-uniform
  const int NV = (mmax_blk >> 2) + 1;                      // V slices per half
  const int NSLICE = 16 + 2 * NV;                          // >= 18 always

  const float scale = 0.044194173824159216f;  // 1/sqrt(512)
  const bf16_t* kbase = k + ((size_t)b * 4096 + kv0) * 512;
  const bf16_t* vbase = vT + ((size_t)b * 512) * 4096 + kv0;

  // stage slice u into SB[buf]; exactly 8 gload_lds16 per thread.
  auto stage_slice = [&](int u, int buf) {
    if (u < 16) {
      // K-slice [512kv x 32d], double-XOR swizzled
#pragma unroll
      for (int rnd = 0; rnd < 8; rnd++) {
        const int ch = rnd * 256 + tid;
        const int g4 = ch >> 4;
        const int w16 = ch & 15;
        const int cg = (w16 >> 2) ^ (g4 & 3);
        const int row = g4 * 4 + (w16 & 3);
        gload_lds16(kbase + (size_t)row * 512 + u * 32 + cg * 8,
                    &SB[buf][ch * 8]);
      }
    } else {
      const int v = u - 16;
      const int dh = (v >= NV) ? 1 : 0;
      const int kvt = v - dh * NV;
      const bf16_t* vb = vbase + (size_t)(dh * 256) * 4096;
      // V^T-slice [256d x 64kv], XOR swizzled
#pragma unroll
      for (int rnd = 0; rnd < 8; rnd++) {
        const int ch = rnd * 256 + tid;
        const int d = ch >> 3;
        const int cg = (ch & 7) ^ (d & 7);
        gload_lds16(vb + (size_t)d * 4096 + kvt * 64 + cg * 8, &SB[buf][ch * 8]);
      }
    }
  };

  // ---- prologue: slices 0,1 in flight (order pinned); Q frags after ------
  stage_slice(0, 0);
  ORDER_FENCE();
  stage_slice(1, 1);
  ORDER_FENCE();

  // Q B-frags: qf[kt] = Q[qrow=l15][kt*32 + quad*8 .. +7]
  bf16x8 qf[16];
  {
    const bf16_t* qp = q + ((size_t)(b * 4096 + t0w + l15)) * 512 + quad * 8;
#pragma unroll
    for (int kk = 0; kk < 16; kk++) qf[kk] = *(const bf16x8*)(qp + kk * 32);
  }

  // ---- Phase 1: S^T accumulate -------------------------------------------
  f32x4 Sacc[32];
#pragma unroll
  for (int m = 0; m < 32; m++) Sacc[m] = f32x4{0.f, 0.f, 0.f, 0.f};

  // per-lane A-frag base (elements); m-stride = 512 elements.
  const int abase =
      ((l15 >> 2) * 16 + (quad ^ ((l15 >> 2) & 3)) * 4 + (l15 & 3)) * 8;

  int cur = 0;
#pragma unroll
  for (int kt = 0; kt < 16; kt++) {
    asm volatile("s_waitcnt vmcnt(8)" ::: "memory");  // slice kt landed
    __builtin_amdgcn_sched_barrier(0);
    __builtin_amdgcn_s_barrier();
    const bf16_t* sb = &SB[cur][0];
#pragma unroll
    for (int m = 0; m < 32; m++) {
      if (m <= mmax) {  // wave-uniform
        const bf16x8 kf = *(const bf16x8*)(sb + abase + m * 512);
        Sacc[m] = MFMA_BF16(kf, qf[kt], Sacc[m]);
      }
    }
    asm volatile("s_waitcnt lgkmcnt(0)" ::: "memory");  // my reads done
    __builtin_amdgcn_sched_barrier(0);
    __builtin_amdgcn_s_barrier();
    stage_slice(kt + 2, cur);  // overwrite just-computed buffer (kt+2 <= 17)
    cur ^= 1;
  }

  // ---- Phase 2: masked softmax (overlaps V slices 16,17 in flight) -------
  const int qr = t0w + l15;
  float mx = NEG_BIG;
#pragma unroll
  for (int m = 0; m < 32; m++) {
    if (m <= mmax) {
#pragma unroll
      for (int r = 0; r < 4; r++) {
        const int kv = kv0 + m * 16 + quad * 4 + r;
        const float vvv = (kv <= qr) ? Sacc[m][r] : NEG_BIG;
        Sacc[m][r] = vvv;
        mx = fmaxf(mx, vvv);
      }
    }
  }
  mx = fmaxf(mx, __shfl_xor(mx, 16));
  mx = fmaxf(mx, __shfl_xor(mx, 32));  // finite: kv0 <= qr always

  float lrow = 0.0f;
  bf16x4 pb[32];
#pragma unroll
  for (int m = 0; m < 32; m++) {
    bf16x4 pv = {};
    if (m <= mmax) {
#pragma unroll
      for (int r = 0; r < 4; r++) {
        const float p = __expf((Sacc[m][r] - mx) * scale);  // masked -> 0
        pv[r] = (bf16_t)p;
        lrow += p;
      }
    }
    pb[m] = pv;
  }
  lrow += __shfl_xor(lrow, 16);
  lrow += __shfl_xor(lrow, 32);

  if (quad == 0)
    stats[((size_t)w * 4 + b) * 64 + wid * 16 + l15] =
        make_float2(mx * scale, lrow);

  // ---- Phase 3: O = P.V, both 256-d halves, unrolled kvt (rule #20) ------
  const int l64 = l15 * 64;
  const int qh = quad >> 1;
  const int ql = (quad & 1) * 4;
  const int s7 = l15 & 7;

#pragma unroll
  for (int dh = 0; dh < 2; dh++) {
    f32x4 Oacc[16];
#pragma unroll
    for (int dt = 0; dt < 16; dt++) Oacc[dt] = f32x4{0.f, 0.f, 0.f, 0.f};

#pragma unroll
    for (int kvt = 0; kvt < 8; kvt++) {
      if (kvt < NV) {  // block-uniform
        const int u = 16 + dh * NV + kvt;
        if (u < NSLICE - 1)
          asm volatile("s_waitcnt vmcnt(8)" ::: "memory");
        else
          asm volatile("s_waitcnt vmcnt(0)" ::: "memory");
        __builtin_amdgcn_sched_barrier(0);
        __builtin_amdgcn_s_barrier();
        if (kvt <= kvtmax) {  // wave-uniform
          const bf16_t* sb = &SB[cur][0];
#pragma unroll
          for (int dt = 0; dt < 16; dt++) {
#pragma unroll
            for (int gg = 0; gg < 4; gg++) {
              const bf16x4 vf = *(const bf16x4*)(
                  sb + dt * 1024 + l64 + (((gg * 2 + qh) ^ s7) << 3) + ql);
              Oacc[dt] = mfma16(pb[kvt * 4 + gg], vf, Oacc[dt]);
            }
          }
        }
        // epilogue on last live kvt: coalesced native-layout stores,
        // issued BEFORE the stage of u+2 so vmcnt ordering stays tight.
        if (kvt == NV - 1) {
          bf16_t* pbase =
              partO + (size_t)obid * 32768 + dh * 16384 + wid * 4096;
#pragma unroll
          for (int dt = 0; dt < 16; dt++) {
            bf16x4 ov;
#pragma unroll
            for (int r = 0; r < 4; r++) ov[r] = (bf16_t)Oacc[dt][r];
            *(bf16x4*)(pbase + dt * 256 + l15 * 16 + quad * 4) = ov;
          }
        }
        asm volatile("s_waitcnt lgkmcnt(0)" ::: "memory");
        __builtin_amdgcn_sched_barrier(0);
        __builtin_amdgcn_s_barrier();
        if (u + 2 < NSLICE) stage_slice(u + 2, cur);
        cur ^= 1;
      }
    }
  }
}

// ---------------------------------------------------------------------------
// Stage 2: combine chunk partials per (b, s); reads partO in native MFMA
// layout (coalesced), normalizes in registers, transposes through a
// row-XOR-swizzled 32 KB LDS bounce, writes coalesced bf16x8 rows.
// ---------------------------------------------------------------------------
__global__ __launch_bounds__(256) void attn_combine_kernel(
    const bf16_t* __restrict__ partO, const float2* __restrict__ stats,
    bf16_t* __restrict__ o) {
  const int b = blockIdx.x & 3;
  const int s = blockIdx.x >> 2;
  const int g = s >> 3;
  const int nc = g + 1;
  const int w0 = 4 * g * (g + 1) + (s & 7) * (g + 1);

  __shared__ float wgt[8][64];
  __shared__ float linv[64];
  __shared__ bf16_t TB[64 * 256];  // 32 KB transpose bounce

  const int tid = threadIdx.x;
  if (tid < 64) {
    float mc[8], lc[8];
    float M = NEG_BIG;
    for (int cc = 0; cc < nc; cc++) {
      const float2 ml = stats[((size_t)(w0 + cc) * 4 + b) * 64 + tid];
      mc[cc] = ml.x;
      lc[cc] = ml.y;
      M = fmaxf(M, ml.x);
    }
    float L = 0.0f;
    for (int cc = 0; cc < nc; cc++) {
      const float wv = __expf(mc[cc] - M);
      wgt[cc][tid] = wv;
      L += wv * lc[cc];
    }
    linv[tid] = (L > 0.0f) ? 1.0f / L : 0.0f;
  }
  __syncthreads();

  // thread decode matching native layout: q-rows q0..q0+3, d = dt*16 + l15
  const int quad = tid & 3;
  const int l15 = (tid >> 2) & 15;
  const int wid = tid >> 6;
  const int q0 = wid * 16 + quad * 4;
  const f32x4 li4 = *(const f32x4*)(&linv[q0]);

  for (int dh = 0; dh < 2; dh++) {
    f32x4 acc4[16] = {};
    for (int cc = 0; cc < nc; cc++) {
      const bf16_t* pp = partO + (size_t)(((w0 + cc) << 2) | b) * 32768 +
                         dh * 16384 + wid * 4096 + l15 * 16 + quad * 4;
      const f32x4 wv4 = *(const f32x4*)(&wgt[cc][q0]);
#pragma unroll
      for (int dt = 0; dt < 16; dt++) {
        const bf16x4 p = *(const bf16x4*)(pp + dt * 256);
#pragma unroll
        for (int e = 0; e < 4; e++) acc4[dt][e] += wv4[e] * (float)p[e];
      }
    }
    // normalize + swizzled bounce write ([64 q][256 d] bf16, row XOR)
#pragma unroll
    for (int dt = 0; dt < 16; dt++) {
      const int d2 = (dt * 16 + l15) * 2;
#pragma unroll
      for (int r = 0; r < 4; r++) {
        const int qq = q0 + r;
        *(bf16_t*)((char*)TB + qq * 512 + (d2 ^ ((qq & 7) << 4))) =
            (bf16_t)(acc4[dt][r] * li4[r]);
      }
    }
    __syncthreads();
    // coalesced read + store
    const int row = tid >> 2;
    const int quarter = tid & 3;
    bf16_t* orow =
        o + ((size_t)(b * 4096 + s * 64 + row)) * 512 + dh * 256 + quarter * 64;
#pragma unroll
    for (int j = 0; j < 8; j++) {
      const int byte = row * 512 + ((quarter * 128 + j * 16) ^ ((row & 7) << 4));
      *(bf16x8*)(orow + j * 8) = *(const bf16x8*)((const char*)TB + byte);
    }
    __syncthreads();  // TB reused next dh
  }
}

// ---------------------------------------------------------------------------
extern "C" void kernel_launch(void* const* d_in, const int* in_sizes, int n_in,
                              void* d_out, int out_size, void* d_ws, size_t ws_size,
                              hipStream_t stream) {
  const float* x_f = (const float*)d_in[0];   // [4,4096,512] fp32
  const float* wq_f = (const float*)d_in[1];  // [1536,512]   fp32
  const float* wp_f = (const float*)d_in[2];  // [512,512]    fp32
  float* out = (float*)d_out;                 // [4,4096,512] fp32

  // ws (bf16 unless noted): xb | wqb | wpb | q | k | vT | partO | stats
  bf16_t* xb = (bf16_t*)d_ws;                      // 16 MB (attn output)
  bf16_t* wqb = xb + (size_t)16384 * 512;          // 1.5 MB
  bf16_t* wpb = wqb + (size_t)1536 * 512;          // 0.5 MB
  bf16_t* q = wpb + (size_t)512 * 512;             // 16 MB
  bf16_t* kk = q + (size_t)16384 * 512;            // 16 MB
  bf16_t* vT = kk + (size_t)16384 * 512;           // 16 MB
  bf16_t* partO = vT + (size_t)16384 * 512;        // 1152*32768*2 = 75.5 MB
  float2* stats = (float2*)(partO + (size_t)1152 * 32768);  // 0.6 MB

  // 0) convert fp32 inputs -> bf16 (single launch)
  cvt3_kernel<<<9216, 256, 0, stream>>>(x_f, wq_f, wp_f, xb, wqb, wpb);

  // 1) qkv = x @ Wqkv^T ; v stored transposed (xb dead afterwards)
  gemm_bt_kernel<0><<<128 * 12, 256, 0, stream>>>(xb, wqb, q, kk, vT, nullptr);
  // 2a) attention partials (R4 pipeline + XCD pinning, no setprio)
  attn_part_kernel<<<1152, 256, 0, stream>>>(q, kk, vT, partO, stats);
  // 2b) combine partials -> xb
  attn_combine_kernel<<<256, 256, 0, stream>>>(partO, stats, xb);
  // 3) y = attn @ Wproj^T -> fp32 d_out
  gemm_bt_kernel<1><<<128 * 4, 256, 0, stream>>>(xb, wpb, nullptr, nullptr, nullptr, out);
}

// Round 9
// 402.633 us; speedup vs baseline: 1.1814x; 1.0748x over previous
//
#include <hip/hip_runtime.h>
#include <hip/hip_bf16.h>
#include <stdint.h>

typedef __bf16 bf16_t;
typedef __bf16 bf16x4 __attribute__((ext_vector_type(4)));
typedef __bf16 bf16x8 __attribute__((ext_vector_type(8)));
typedef short s16x4 __attribute__((ext_vector_type(4)));
typedef float f32x4 __attribute__((ext_vector_type(4)));

static_assert(sizeof(bf16x8) == 16, "bf16x8 must be 16B");

#define MFMA_BF16(a, b, c) __builtin_amdgcn_mfma_f32_16x16x32_bf16((a), (b), (c), 0, 0, 0)

// 16x16x16 bf16 MFMA (A[m=l15][k=quad*4+i], B[k=quad*4+i][n=l15],
// C/D row=quad*4+r col=l15)
__device__ __forceinline__ f32x4 mfma16(bf16x4 a, bf16x4 b, f32x4 c) {
#if __has_builtin(__builtin_amdgcn_mfma_f32_16x16x16bf16_1k)
  union { bf16x4 h; s16x4 s; } ua, ub;
  ua.h = a;
  ub.h = b;
  return __builtin_amdgcn_mfma_f32_16x16x16bf16_1k(ua.s, ub.s, c, 0, 0, 0);
#else
  f32x4 d = c;
  asm volatile("v_mfma_f32_16x16x16_bf16 %0, %1, %2, %0" : "+v"(d) : "v"(a), "v"(b));
  return d;
#endif
}

typedef const __attribute__((address_space(1))) void* gas_ptr;
typedef __attribute__((address_space(3))) void* las_ptr;

__device__ __forceinline__ void gload_lds16(const void* g, void* l) {
  __builtin_amdgcn_global_load_lds((gas_ptr)g, (las_ptr)l, 16, 0, 0);
}

// compile-time memory-op ordering fence (pins global_load_lds issue order)
#define ORDER_FENCE() asm volatile("" ::: "memory")

#define NEG_BIG (-1.0e30f)

// ---------------------------------------------------------------------------
// fp32 -> bf16 convert, all three inputs in one launch.
// ---------------------------------------------------------------------------
__global__ __launch_bounds__(256) void cvt3_kernel(
    const float* __restrict__ x, const float* __restrict__ wq,
    const float* __restrict__ wp, bf16_t* __restrict__ xb,
    bf16_t* __restrict__ wqb, bf16_t* __restrict__ wpb) {
  const int i = (blockIdx.x * 256 + threadIdx.x) * 4;
  const float* src;
  bf16_t* dst;
  int off;
  if (i < 8388608) {
    src = x; dst = xb; off = 0;
  } else if (i < 9175040) {
    src = wq; dst = wqb; off = 8388608;
  } else {
    src = wp; dst = wpb; off = 9175040;
  }
  const f32x4 v = *(const f32x4*)(src + (i - off));
  bf16x4 o;
  o[0] = (bf16_t)v[0];
  o[1] = (bf16_t)v[1];
  o[2] = (bf16_t)v[2];
  o[3] = (bf16_t)v[3];
  *(bf16x4*)(dst + (i - off)) = o;
}

// ---------------------------------------------------------------------------
// GEMM (m97 structure): D[m][n] = sum_k A[m][k] * Bw[n][k]
// MODE 0: qkv -> q / k row-major, v transposed to vT[b][d][t].
//   Epilogue bounces the tile through LDS for COALESCED stores:
//   v-blocks (nt>=8): [64 d][128 t] XOR tile -> full 128-B vT row runs
//   q/k-blocks:       [128 t][64 d] XOR tile -> 64-B row runs
//   (replaces 2-B scattered stores that caused TCC RMW amplification)
// MODE 1: final epilogue -> o_f as FP32 (unchanged)
// ---------------------------------------------------------------------------
template <int MODE>
__global__ __launch_bounds__(256, 2) void gemm_bt_kernel(
    const bf16_t* __restrict__ A, const bf16_t* __restrict__ Bw,
    bf16_t* __restrict__ o_q, bf16_t* __restrict__ o_k, bf16_t* __restrict__ o_vT,
    float* __restrict__ o_f) {
  constexpr int K = 512;
  __shared__ bf16_t AB[2 * 128 * 32];  // As | Bs ; reused as 16-KB bounce tile
  bf16_t* As = AB;
  bf16_t* Bs = AB + 128 * 32;

  const int tid = threadIdx.x;
  const int lane = tid & 63;
  const int wid = tid >> 6;
  const int quad = lane >> 4;
  const int l15 = lane & 15;
  const int wm = wid >> 1;
  const int wn = wid & 1;

  const int mt = blockIdx.x & 127;
  const int nt = blockIdx.x >> 7;
  const int row0 = mt * 128;
  const int col0 = nt * 128;

  f32x4 acc[4][4] = {};

  for (int kt = 0; kt < K; kt += 32) {
    __syncthreads();
#pragma unroll
    for (int rnd = 0; rnd < 2; rnd++) {
      const int e = (rnd * 256 + tid) * 8;
      const int r = e >> 5;
      const int c = e & 31;
      gload_lds16(A + (size_t)(row0 + r) * K + kt + c, As + e);
      gload_lds16(Bw + (size_t)(col0 + r) * K + kt + c, Bs + e);
    }
    __syncthreads();

    bf16x8 af[4], bfr[4];
#pragma unroll
    for (int i = 0; i < 4; i++)
      af[i] = *(const bf16x8*)(As + (wm * 64 + i * 16 + l15) * 32 + quad * 8);
#pragma unroll
    for (int i = 0; i < 4; i++)
      bfr[i] = *(const bf16x8*)(Bs + (wn * 64 + i * 16 + l15) * 32 + quad * 8);
#pragma unroll
    for (int mi = 0; mi < 4; mi++)
#pragma unroll
      for (int ni = 0; ni < 4; ni++)
        acc[mi][ni] = MFMA_BF16(af[mi], bfr[ni], acc[mi][ni]);
  }

  if constexpr (MODE == 1) {
#pragma unroll
    for (int mi = 0; mi < 4; mi++) {
      const int row = row0 + wm * 64 + mi * 16 + quad * 4;
#pragma unroll
      for (int ni = 0; ni < 4; ni++) {
        const int col = col0 + wn * 64 + ni * 16 + l15;
#pragma unroll
        for (int r = 0; r < 4; r++)
          o_f[(size_t)(row + r) * 512 + col] = acc[mi][ni][r];
      }
    }
  } else {
    // ---- LDS-bounce coalesced epilogue (two 64-col halves) ----------------
    const bool isv = (nt >= 8);
    bf16_t* T = AB;  // 8192 bf16 = 16 KB
    __syncthreads();  // As/Bs dead
#pragma unroll
    for (int hh = 0; hh < 2; hh++) {
      if (wn == hh) {
        if (isv) {
          // tile [64 d][128 t], t XOR (d&15)<<3, vector bf16x4 writes
#pragma unroll
          for (int mi = 0; mi < 4; mi++)
#pragma unroll
            for (int ni = 0; ni < 4; ni++) {
              const int d_rel = ni * 16 + l15;
              const int trow = wm * 64 + mi * 16 + quad * 4;
              bf16x4 ov;
#pragma unroll
              for (int r = 0; r < 4; r++) ov[r] = (bf16_t)acc[mi][ni][r];
              *(bf16x4*)(T + d_rel * 128 + (trow ^ ((d_rel & 15) << 3))) = ov;
            }
        } else {
          // tile [128 t][64 d], d XOR (trow&7)<<3, scalar writes
#pragma unroll
          for (int mi = 0; mi < 4; mi++)
#pragma unroll
            for (int ni = 0; ni < 4; ni++)
#pragma unroll
              for (int r = 0; r < 4; r++) {
                const int d_rel = ni * 16 + l15;
                const int trow = wm * 64 + mi * 16 + quad * 4 + r;
                T[trow * 64 + (d_rel ^ ((trow & 7) << 3))] =
                    (bf16_t)acc[mi][ni][r];
              }
        }
      }
      __syncthreads();
      if (isv) {
        // 8 lanes x 16 B = full 128-B contiguous vT row runs
        const int bb = row0 >> 12;
        const int t0 = row0 & 4095;
#pragma unroll
        for (int p = 0; p < 2; p++) {
          const int d = p * 32 + (tid >> 3);
          bf16_t* vrow =
              o_vT + ((size_t)(bb * 512 + col0 - 1024 + hh * 64 + d)) * 4096 + t0;
#pragma unroll
          for (int j = 0; j < 2; j++) {
            const int t8 = (tid & 7) * 8 + j * 64;
            *(bf16x8*)(vrow + t8) =
                *(const bf16x8*)(T + d * 128 + (t8 ^ ((d & 15) << 3)));
          }
        }
      } else {
        bf16_t* dstp = (nt < 4) ? o_q : o_k;
        const int cbase = col0 - ((nt < 4) ? 0 : 512) + hh * 64;
#pragma unroll
        for (int p = 0; p < 2; p++) {
          const int rrow = p * 64 + (tid >> 2);
          bf16_t* drow = dstp + (size_t)(row0 + rrow) * 512 + cbase;
#pragma unroll
          for (int j = 0; j < 2; j++) {
            const int c8 = (tid & 3) * 8 + j * 32;
            *(bf16x8*)(drow + c8) =
                *(const bf16x8*)(T + rrow * 64 + (c8 ^ ((rrow & 7) << 3)));
          }
        }
      }
      __syncthreads();  // T reused for next half
    }
  }
}

// ---------------------------------------------------------------------------
// Split-KV flash attention stage 1 — counted-vmcnt raw-barrier pipeline
// (R4 body = best measured) + reuse-aware XCD placement (R8: FETCH 108->47 MB).
// partO/stats keep legacy (w, b) indexing -> combine unchanged.
// ---------------------------------------------------------------------------
__global__ __launch_bounds__(256, 2) void attn_part_kernel(
    const bf16_t* __restrict__ q, const bf16_t* __restrict__ k,
    const bf16_t* __restrict__ vT, bf16_t* __restrict__ partO,
    float2* __restrict__ stats) {
  __shared__ bf16_t SB[2][16384];  // 2 x 32 KB double buffer

  const int tid = threadIdx.x;
  const int lane = tid & 63;
  const int wid = tid >> 6;
  const int quad = lane >> 4;
  const int l15 = lane & 15;

  // ---- reuse-aware decode: bid -> (b, s, c); groups (b,c) pinned per XCD --
  const int x = blockIdx.x & 7;   // XCD (round-robin)
  const int n = blockIdx.x >> 3;  // 0..143 within XCD
  const int b = x >> 1;
  int c, i;
  if ((x & 1) == 0) {             // c in {0,2,4}: sizes 64,48,32
    if (n < 64)       { c = 0; i = n; }
    else if (n < 112) { c = 2; i = n - 64; }
    else              { c = 4; i = n - 112; }
  } else {                        // c in {1,3,5,6,7}: sizes 56,40,24,16,8
    if (n < 56)       { c = 1; i = n; }
    else if (n < 96)  { c = 3; i = n - 56; }
    else if (n < 120) { c = 5; i = n - 96; }
    else if (n < 136) { c = 6; i = n - 120; }
    else              { c = 7; i = n - 136; }
  }
  const int s = 8 * c + i;        // valid strips for chunk c are s >= 8c
  const int g = s >> 3;
  const int w = 4 * g * (g + 1) + (s & 7) * (g + 1) + c;  // legacy index
  const int obid = (w << 2) | b;                          // legacy partO slot

  const int t0w = s * 64 + wid * 16;  // this wave's q rows
  const int kv0 = c * 512;
  const int mmax = min(31, (t0w + 15 - kv0) >> 4);         // wave-uniform
  const int kvtmax = mmax >> 2;                            // wave-uniform
  const int mmax_blk = min(31, (s * 64 + 63 - kv0) >> 4);  // block-uniform
  const int NV = (mmax_blk >> 2) + 1;                      // V slices per half
  const int NSLICE = 16 + 2 * NV;                          // >= 18 always

  const float scale = 0.044194173824159216f;  // 1/sqrt(512)
  const bf16_t* kbase = k + ((size_t)b * 4096 + kv0) * 512;
  const bf16_t* vbase = vT + ((size_t)b * 512) * 4096 + kv0;

  // stage slice u into SB[buf]; exactly 8 gload_lds16 per thread.
  auto stage_slice = [&](int u, int buf) {
    if (u < 16) {
      // K-slice [512kv x 32d], double-XOR swizzled
#pragma unroll
      for (int rnd = 0; rnd < 8; rnd++) {
        const int ch = rnd * 256 + tid;
        const int g4 = ch >> 4;
        const int w16 = ch & 15;
        const int cg = (w16 >> 2) ^ (g4 & 3);
        const int row = g4 * 4 + (w16 & 3);
        gload_lds16(kbase + (size_t)row * 512 + u * 32 + cg * 8,
                    &SB[buf][ch * 8]);
      }
    } else {
      const int v = u - 16;
      const int dh = (v >= NV) ? 1 : 0;
      const int kvt = v - dh * NV;
      const bf16_t* vb = vbase + (size_t)(dh * 256) * 4096;
      // V^T-slice [256d x 64kv], XOR swizzled
#pragma unroll
      for (int rnd = 0; rnd < 8; rnd++) {
        const int ch = rnd * 256 + tid;
        const int d = ch >> 3;
        const int cg = (ch & 7) ^ (d & 7);
        gload_lds16(vb + (size_t)d * 4096 + kvt * 64 + cg * 8, &SB[buf][ch * 8]);
      }
    }
  };

  // ---- prologue: slices 0,1 in flight (order pinned); Q frags after ------
  stage_slice(0, 0);
  ORDER_FENCE();
  stage_slice(1, 1);
  ORDER_FENCE();

  // Q B-frags: qf[kt] = Q[qrow=l15][kt*32 + quad*8 .. +7]
  bf16x8 qf[16];
  {
    const bf16_t* qp = q + ((size_t)(b * 4096 + t0w + l15)) * 512 + quad * 8;
#pragma unroll
    for (int kk = 0; kk < 16; kk++) qf[kk] = *(const bf16x8*)(qp + kk * 32);
  }

  // ---- Phase 1: S^T accumulate -------------------------------------------
  f32x4 Sacc[32];
#pragma unroll
  for (int m = 0; m < 32; m++) Sacc[m] = f32x4{0.f, 0.f, 0.f, 0.f};

  // per-lane A-frag base (elements); m-stride = 512 elements.
  const int abase =
      ((l15 >> 2) * 16 + (quad ^ ((l15 >> 2) & 3)) * 4 + (l15 & 3)) * 8;

  int cur = 0;
#pragma unroll
  for (int kt = 0; kt < 16; kt++) {
    asm volatile("s_waitcnt vmcnt(8)" ::: "memory");  // slice kt landed
    __builtin_amdgcn_sched_barrier(0);
    __builtin_amdgcn_s_barrier();
    const bf16_t* sb = &SB[cur][0];
#pragma unroll
    for (int m = 0; m < 32; m++) {
      if (m <= mmax) {  // wave-uniform
        const bf16x8 kf = *(const bf16x8*)(sb + abase + m * 512);
        Sacc[m] = MFMA_BF16(kf, qf[kt], Sacc[m]);
      }
    }
    asm volatile("s_waitcnt lgkmcnt(0)" ::: "memory");  // my reads done
    __builtin_amdgcn_sched_barrier(0);
    __builtin_amdgcn_s_barrier();
    stage_slice(kt + 2, cur);  // overwrite just-computed buffer (kt+2 <= 17)
    cur ^= 1;
  }

  // ---- Phase 2: masked softmax (overlaps V slices 16,17 in flight) -------
  const int qr = t0w + l15;
  float mx = NEG_BIG;
#pragma unroll
  for (int m = 0; m < 32; m++) {
    if (m <= mmax) {
#pragma unroll
      for (int r = 0; r < 4; r++) {
        const int kv = kv0 + m * 16 + quad * 4 + r;
        const float vvv = (kv <= qr) ? Sacc[m][r] : NEG_BIG;
        Sacc[m][r] = vvv;
        mx = fmaxf(mx, vvv);
      }
    }
  }
  mx = fmaxf(mx, __shfl_xor(mx, 16));
  mx = fmaxf(mx, __shfl_xor(mx, 32));  // finite: kv0 <= qr always

  float lrow = 0.0f;
  bf16x4 pb[32];
#pragma unroll
  for (int m = 0; m < 32; m++) {
    bf16x4 pv = {};
    if (m <= mmax) {
#pragma unroll
      for (int r = 0; r < 4; r++) {
        const float p = __expf((Sacc[m][r] - mx) * scale);  // masked -> 0
        pv[r] = (bf16_t)p;
        lrow += p;
      }
    }
    pb[m] = pv;
  }
  lrow += __shfl_xor(lrow, 16);
  lrow += __shfl_xor(lrow, 32);

  if (quad == 0)
    stats[((size_t)w * 4 + b) * 64 + wid * 16 + l15] =
        make_float2(mx * scale, lrow);

  // ---- Phase 3: O = P.V, both 256-d halves, unrolled kvt (rule #20) ------
  const int l64 = l15 * 64;
  const int qh = quad >> 1;
  const int ql = (quad & 1) * 4;
  const int s7 = l15 & 7;

#pragma unroll
  for (int dh = 0; dh < 2; dh++) {
    f32x4 Oacc[16];
#pragma unroll
    for (int dt = 0; dt < 16; dt++) Oacc[dt] = f32x4{0.f, 0.f, 0.f, 0.f};

#pragma unroll
    for (int kvt = 0; kvt < 8; kvt++) {
      if (kvt < NV) {  // block-uniform
        const int u = 16 + dh * NV + kvt;
        if (u < NSLICE - 1)
          asm volatile("s_waitcnt vmcnt(8)" ::: "memory");
        else
          asm volatile("s_waitcnt vmcnt(0)" ::: "memory");
        __builtin_amdgcn_sched_barrier(0);
        __builtin_amdgcn_s_barrier();
        if (kvt <= kvtmax) {  // wave-uniform
          const bf16_t* sb = &SB[cur][0];
#pragma unroll
          for (int dt = 0; dt < 16; dt++) {
#pragma unroll
            for (int gg = 0; gg < 4; gg++) {
              const bf16x4 vf = *(const bf16x4*)(
                  sb + dt * 1024 + l64 + (((gg * 2 + qh) ^ s7) << 3) + ql);
              Oacc[dt] = mfma16(pb[kvt * 4 + gg], vf, Oacc[dt]);
            }
          }
        }
        // epilogue on last live kvt: coalesced native-layout stores,
        // issued BEFORE the stage of u+2 so vmcnt ordering stays tight.
        if (kvt == NV - 1) {
          bf16_t* pbase =
              partO + (size_t)obid * 32768 + dh * 16384 + wid * 4096;
#pragma unroll
          for (int dt = 0; dt < 16; dt++) {
            bf16x4 ov;
#pragma unroll
            for (int r = 0; r < 4; r++) ov[r] = (bf16_t)Oacc[dt][r];
            *(bf16x4*)(pbase + dt * 256 + l15 * 16 + quad * 4) = ov;
          }
        }
        asm volatile("s_waitcnt lgkmcnt(0)" ::: "memory");
        __builtin_amdgcn_sched_barrier(0);
        __builtin_amdgcn_s_barrier();
        if (u + 2 < NSLICE) stage_slice(u + 2, cur);
        cur ^= 1;
      }
    }
  }
}

// ---------------------------------------------------------------------------
// Stage 2: combine chunk partials per (b, s); reads partO in native MFMA
// layout (coalesced), normalizes in registers, transposes through a
// row-XOR-swizzled 32 KB LDS bounce, writes coalesced bf16x8 rows.
// ---------------------------------------------------------------------------
__global__ __launch_bounds__(256) void attn_combine_kernel(
    const bf16_t* __restrict__ partO, const float2* __restrict__ stats,
    bf16_t* __restrict__ o) {
  const int b = blockIdx.x & 3;
  const int s = blockIdx.x >> 2;
  const int g = s >> 3;
  const int nc = g + 1;
  const int w0 = 4 * g * (g + 1) + (s & 7) * (g + 1);

  __shared__ float wgt[8][64];
  __shared__ float linv[64];
  __shared__ bf16_t TB[64 * 256];  // 32 KB transpose bounce

  const int tid = threadIdx.x;
  if (tid < 64) {
    float mc[8], lc[8];
    float M = NEG_BIG;
    for (int cc = 0; cc < nc; cc++) {
      const float2 ml = stats[((size_t)(w0 + cc) * 4 + b) * 64 + tid];
      mc[cc] = ml.x;
      lc[cc] = ml.y;
      M = fmaxf(M, ml.x);
    }
    float L = 0.0f;
    for (int cc = 0; cc < nc; cc++) {
      const float wv = __expf(mc[cc] - M);
      wgt[cc][tid] = wv;
      L += wv * lc[cc];
    }
    linv[tid] = (L > 0.0f) ? 1.0f / L : 0.0f;
  }
  __syncthreads();

  // thread decode matching native layout: q-rows q0..q0+3, d = dt*16 + l15
  const int quad = tid & 3;
  const int l15 = (tid >> 2) & 15;
  const int wid = tid >> 6;
  const int q0 = wid * 16 + quad * 4;
  const f32x4 li4 = *(const f32x4*)(&linv[q0]);

  for (int dh = 0; dh < 2; dh++) {
    f32x4 acc4[16] = {};
    for (int cc = 0; cc < nc; cc++) {
      const bf16_t* pp = partO + (size_t)(((w0 + cc) << 2) | b) * 32768 +
                         dh * 16384 + wid * 4096 + l15 * 16 + quad * 4;
      const f32x4 wv4 = *(const f32x4*)(&wgt[cc][q0]);
#pragma unroll
      for (int dt = 0; dt < 16; dt++) {
        const bf16x4 p = *(const bf16x4*)(pp + dt * 256);
#pragma unroll
        for (int e = 0; e < 4; e++) acc4[dt][e] += wv4[e] * (float)p[e];
      }
    }
    // normalize + swizzled bounce write ([64 q][256 d] bf16, row XOR)
#pragma unroll
    for (int dt = 0; dt < 16; dt++) {
      const int d2 = (dt * 16 + l15) * 2;
#pragma unroll
      for (int r = 0; r < 4; r++) {
        const int qq = q0 + r;
        *(bf16_t*)((char*)TB + qq * 512 + (d2 ^ ((qq & 7) << 4))) =
            (bf16_t)(acc4[dt][r] * li4[r]);
      }
    }
    __syncthreads();
    // coalesced read + store
    const int row = tid >> 2;
    const int quarter = tid & 3;
    bf16_t* orow =
        o + ((size_t)(b * 4096 + s * 64 + row)) * 512 + dh * 256 + quarter * 64;
#pragma unroll
    for (int j = 0; j < 8; j++) {
      const int byte = row * 512 + ((quarter * 128 + j * 16) ^ ((row & 7) << 4));
      *(bf16x8*)(orow + j * 8) = *(const bf16x8*)((const char*)TB + byte);
    }
    __syncthreads();  // TB reused next dh
  }
}

// ---------------------------------------------------------------------------
extern "C" void kernel_launch(void* const* d_in, const int* in_sizes, int n_in,
                              void* d_out, int out_size, void* d_ws, size_t ws_size,
                              hipStream_t stream) {
  const float* x_f = (const float*)d_in[0];   // [4,4096,512] fp32
  const float* wq_f = (const float*)d_in[1];  // [1536,512]   fp32
  const float* wp_f = (const float*)d_in[2];  // [512,512]    fp32
  float* out = (float*)d_out;                 // [4,4096,512] fp32

  // ws (bf16 unless noted): xb | wqb | wpb | q | k | vT | partO | stats
  bf16_t* xb = (bf16_t*)d_ws;                      // 16 MB (attn output)
  bf16_t* wqb = xb + (size_t)16384 * 512;          // 1.5 MB
  bf16_t* wpb = wqb + (size_t)1536 * 512;          // 0.5 MB
  bf16_t* q = wpb + (size_t)512 * 512;             // 16 MB
  bf16_t* kk = q + (size_t)16384 * 512;            // 16 MB
  bf16_t* vT = kk + (size_t)16384 * 512;           // 16 MB
  bf16_t* partO = vT + (size_t)16384 * 512;        // 1152*32768*2 = 75.5 MB
  float2* stats = (float2*)(partO + (size_t)1152 * 32768);  // 0.6 MB

  // 0) convert fp32 inputs -> bf16 (single launch)
  cvt3_kernel<<<9216, 256, 0, stream>>>(x_f, wq_f, wp_f, xb, wqb, wpb);

  // 1) qkv = x @ Wqkv^T ; v stored transposed (coalesced bounce epilogue)
  gemm_bt_kernel<0><<<128 * 12, 256, 0, stream>>>(xb, wqb, q, kk, vT, nullptr);
  // 2a) attention partials (R4 pipeline + XCD pinning)
  attn_part_kernel<<<1152, 256, 0, stream>>>(q, kk, vT, partO, stats);
  // 2b) combine partials -> xb
  attn_combine_kernel<<<256, 256, 0, stream>>>(partO, stats, xb);
  // 3) y = attn @ Wproj^T -> fp32 d_out
  gemm_bt_kernel<1><<<128 * 4, 256, 0, stream>>>(xb, wpb, nullptr, nullptr, nullptr, out);
}

// Round 10
// 382.347 us; speedup vs baseline: 1.2441x; 1.0531x over previous
//
#include <hip/hip_runtime.h>
#include <hip/hip_bf16.h>
#include <stdint.h>

typedef __bf16 bf16_t;
typedef __bf16 bf16x4 __attribute__((ext_vector_type(4)));
typedef __bf16 bf16x8 __attribute__((ext_vector_type(8)));
typedef short s16x4 __attribute__((ext_vector_type(4)));
typedef float f32x4 __attribute__((ext_vector_type(4)));

static_assert(sizeof(bf16x8) == 16, "bf16x8 must be 16B");

#define MFMA_BF16(a, b, c) __builtin_amdgcn_mfma_f32_16x16x32_bf16((a), (b), (c), 0, 0, 0)

// 16x16x16 bf16 MFMA (A[m=l15][k=quad*4+i], B[k=quad*4+i][n=l15],
// C/D row=quad*4+r col=l15)
__device__ __forceinline__ f32x4 mfma16(bf16x4 a, bf16x4 b, f32x4 c) {
#if __has_builtin(__builtin_amdgcn_mfma_f32_16x16x16bf16_1k)
  union { bf16x4 h; s16x4 s; } ua, ub;
  ua.h = a;
  ub.h = b;
  return __builtin_amdgcn_mfma_f32_16x16x16bf16_1k(ua.s, ub.s, c, 0, 0, 0);
#else
  f32x4 d = c;
  asm volatile("v_mfma_f32_16x16x16_bf16 %0, %1, %2, %0" : "+v"(d) : "v"(a), "v"(b));
  return d;
#endif
}

typedef const __attribute__((address_space(1))) void* gas_ptr;
typedef __attribute__((address_space(3))) void* las_ptr;

__device__ __forceinline__ void gload_lds16(const void* g, void* l) {
  __builtin_amdgcn_global_load_lds((gas_ptr)g, (las_ptr)l, 16, 0, 0);
}

// compile-time memory-op ordering fence (pins global_load_lds issue order)
#define ORDER_FENCE() asm volatile("" ::: "memory")

#define NEG_BIG (-1.0e30f)

// ---------------------------------------------------------------------------
// fp32 -> bf16 convert, all three inputs in one launch.
// ---------------------------------------------------------------------------
__global__ __launch_bounds__(256) void cvt3_kernel(
    const float* __restrict__ x, const float* __restrict__ wq,
    const float* __restrict__ wp, bf16_t* __restrict__ xb,
    bf16_t* __restrict__ wqb, bf16_t* __restrict__ wpb) {
  const int i = (blockIdx.x * 256 + threadIdx.x) * 4;
  const float* src;
  bf16_t* dst;
  int off;
  if (i < 8388608) {
    src = x; dst = xb; off = 0;
  } else if (i < 9175040) {
    src = wq; dst = wqb; off = 8388608;
  } else {
    src = wp; dst = wpb; off = 9175040;
  }
  const f32x4 v = *(const f32x4*)(src + (i - off));
  bf16x4 o;
  o[0] = (bf16_t)v[0];
  o[1] = (bf16_t)v[1];
  o[2] = (bf16_t)v[2];
  o[3] = (bf16_t)v[3];
  *(bf16x4*)(dst + (i - off)) = o;
}

// ---------------------------------------------------------------------------
// GEMM (m97 structure): D[m][n] = sum_k A[m][k] * Bw[n][k]
// MODE 0: qkv -> q / k row-major, v transposed to vT[b][d][t];
//   LDS-bounce coalesced epilogue (R9: +30 us end-to-end).
// MODE 1: final epilogue -> o_f as FP32.
// ---------------------------------------------------------------------------
template <int MODE>
__global__ __launch_bounds__(256, 2) void gemm_bt_kernel(
    const bf16_t* __restrict__ A, const bf16_t* __restrict__ Bw,
    bf16_t* __restrict__ o_q, bf16_t* __restrict__ o_k, bf16_t* __restrict__ o_vT,
    float* __restrict__ o_f) {
  constexpr int K = 512;
  __shared__ bf16_t AB[2 * 128 * 32];  // As | Bs ; reused as 16-KB bounce tile
  bf16_t* As = AB;
  bf16_t* Bs = AB + 128 * 32;

  const int tid = threadIdx.x;
  const int lane = tid & 63;
  const int wid = tid >> 6;
  const int quad = lane >> 4;
  const int l15 = lane & 15;
  const int wm = wid >> 1;
  const int wn = wid & 1;

  const int mt = blockIdx.x & 127;
  const int nt = blockIdx.x >> 7;
  const int row0 = mt * 128;
  const int col0 = nt * 128;

  f32x4 acc[4][4] = {};

  for (int kt = 0; kt < K; kt += 32) {
    __syncthreads();
#pragma unroll
    for (int rnd = 0; rnd < 2; rnd++) {
      const int e = (rnd * 256 + tid) * 8;
      const int r = e >> 5;
      const int c = e & 31;
      gload_lds16(A + (size_t)(row0 + r) * K + kt + c, As + e);
      gload_lds16(Bw + (size_t)(col0 + r) * K + kt + c, Bs + e);
    }
    __syncthreads();

    bf16x8 af[4], bfr[4];
#pragma unroll
    for (int i = 0; i < 4; i++)
      af[i] = *(const bf16x8*)(As + (wm * 64 + i * 16 + l15) * 32 + quad * 8);
#pragma unroll
    for (int i = 0; i < 4; i++)
      bfr[i] = *(const bf16x8*)(Bs + (wn * 64 + i * 16 + l15) * 32 + quad * 8);
#pragma unroll
    for (int mi = 0; mi < 4; mi++)
#pragma unroll
      for (int ni = 0; ni < 4; ni++)
        acc[mi][ni] = MFMA_BF16(af[mi], bfr[ni], acc[mi][ni]);
  }

  if constexpr (MODE == 1) {
#pragma unroll
    for (int mi = 0; mi < 4; mi++) {
      const int row = row0 + wm * 64 + mi * 16 + quad * 4;
#pragma unroll
      for (int ni = 0; ni < 4; ni++) {
        const int col = col0 + wn * 64 + ni * 16 + l15;
#pragma unroll
        for (int r = 0; r < 4; r++)
          o_f[(size_t)(row + r) * 512 + col] = acc[mi][ni][r];
      }
    }
  } else {
    // ---- LDS-bounce coalesced epilogue (two 64-col halves) ----------------
    const bool isv = (nt >= 8);
    bf16_t* T = AB;  // 8192 bf16 = 16 KB
    __syncthreads();  // As/Bs dead
#pragma unroll
    for (int hh = 0; hh < 2; hh++) {
      if (wn == hh) {
        if (isv) {
          // tile [64 d][128 t], t XOR (d&15)<<3, vector bf16x4 writes
#pragma unroll
          for (int mi = 0; mi < 4; mi++)
#pragma unroll
            for (int ni = 0; ni < 4; ni++) {
              const int d_rel = ni * 16 + l15;
              const int trow = wm * 64 + mi * 16 + quad * 4;
              bf16x4 ov;
#pragma unroll
              for (int r = 0; r < 4; r++) ov[r] = (bf16_t)acc[mi][ni][r];
              *(bf16x4*)(T + d_rel * 128 + (trow ^ ((d_rel & 15) << 3))) = ov;
            }
        } else {
          // tile [128 t][64 d], d XOR (trow&7)<<3, scalar writes
#pragma unroll
          for (int mi = 0; mi < 4; mi++)
#pragma unroll
            for (int ni = 0; ni < 4; ni++)
#pragma unroll
              for (int r = 0; r < 4; r++) {
                const int d_rel = ni * 16 + l15;
                const int trow = wm * 64 + mi * 16 + quad * 4 + r;
                T[trow * 64 + (d_rel ^ ((trow & 7) << 3))] =
                    (bf16_t)acc[mi][ni][r];
              }
        }
      }
      __syncthreads();
      if (isv) {
        // 8 lanes x 16 B = full 128-B contiguous vT row runs
        const int bb = row0 >> 12;
        const int t0 = row0 & 4095;
#pragma unroll
        for (int p = 0; p < 2; p++) {
          const int d = p * 32 + (tid >> 3);
          bf16_t* vrow =
              o_vT + ((size_t)(bb * 512 + col0 - 1024 + hh * 64 + d)) * 4096 + t0;
#pragma unroll
          for (int j = 0; j < 2; j++) {
            const int t8 = (tid & 7) * 8 + j * 64;
            *(bf16x8*)(vrow + t8) =
                *(const bf16x8*)(T + d * 128 + (t8 ^ ((d & 15) << 3)));
          }
        }
      } else {
        bf16_t* dstp = (nt < 4) ? o_q : o_k;
        const int cbase = col0 - ((nt < 4) ? 0 : 512) + hh * 64;
#pragma unroll
        for (int p = 0; p < 2; p++) {
          const int rrow = p * 64 + (tid >> 2);
          bf16_t* drow = dstp + (size_t)(row0 + rrow) * 512 + cbase;
#pragma unroll
          for (int j = 0; j < 2; j++) {
            const int c8 = (tid & 3) * 8 + j * 32;
            *(bf16x8*)(drow + c8) =
                *(const bf16x8*)(T + rrow * 64 + (c8 ^ ((rrow & 7) << 3)));
          }
        }
      }
      __syncthreads();  // T reused for next half
    }
  }
}

// ---------------------------------------------------------------------------
// Split-KV flash attention stage 1 — QBLK=128: 512 threads / 8 waves share
// each staged 32-KB slice (2x compute per staged byte vs QBLK=64; per-CU
// staging pressure halves). Pipeline skeleton identical to R4/R9:
// counted-vmcnt (now vmcnt(4): 4 loads/thread/slice), raw barriers,
// prefetch distance 2, native-layout partO stores.
// Block (b, s, c): s = 128-row strip (0..31), c = 512-kv chunk. Grid = 576,
// (b,c)-balanced XCD pinning: even XCD c in {0,3,5,6}, odd c in {1,2,4,7}
// (72 blocks each). Outputs land in the legacy 64-row (w, b) partO slots:
// waves 0-3 -> half-strip 2s, waves 4-7 -> 2s+1. Combine format unchanged.
// ---------------------------------------------------------------------------
__global__ __launch_bounds__(512, 2) void attn_part_kernel(
    const bf16_t* __restrict__ q, const bf16_t* __restrict__ k,
    const bf16_t* __restrict__ vT, bf16_t* __restrict__ partO,
    float2* __restrict__ stats) {
  __shared__ bf16_t SB[2][16384];  // 2 x 32 KB double buffer

  const int tid = threadIdx.x;
  const int lane = tid & 63;
  const int wid = tid >> 6;   // 0..7
  const int quad = lane >> 4;
  const int l15 = lane & 15;

  // ---- decode: bid -> (b, s, c); (b,c) groups pinned per XCD --------------
  const int x = blockIdx.x & 7;   // XCD (round-robin)
  const int n = blockIdx.x >> 3;  // 0..71 within XCD
  const int b = x >> 1;
  int c, i;
  if ((x & 1) == 0) {             // c in {0,3,5,6}: sizes 32,20,12,8
    if (n < 32)      { c = 0; i = n; }
    else if (n < 52) { c = 3; i = n - 32; }
    else if (n < 64) { c = 5; i = n - 52; }
    else             { c = 6; i = n - 64; }
  } else {                        // c in {1,2,4,7}: sizes 28,24,16,4
    if (n < 28)      { c = 1; i = n; }
    else if (n < 52) { c = 2; i = n - 28; }
    else if (n < 68) { c = 4; i = n - 52; }
    else             { c = 7; i = n - 68; }
  }
  const int s = 4 * c + i;        // strip 0..31 (128 q rows); s >= 4c

  // legacy 64-row-strip indices for the two half-strips
  const int g = s >> 2;                         // = (2s)>>3 = (2s+1)>>3
  const int wA = 4 * g * (g + 1) + ((2 * s) & 7) * (g + 1) + c;
  const int wlocal = (wid < 4) ? wA : wA + (g + 1);
  const int obid = (wlocal << 2) | b;
  const int wid4 = wid & 3;

  const int t0w = s * 128 + wid * 16;  // this wave's q rows
  const int kv0 = c * 512;
  const int mmax = min(31, (t0w + 15 - kv0) >> 4);           // wave-uniform
  const int kvtmax = mmax >> 2;                              // wave-uniform
  const int mmax_blk = min(31, (s * 128 + 127 - kv0) >> 4);  // block-uniform
  const int NV = (mmax_blk >> 2) + 1;                        // V slices/half, >=2
  const int NSLICE = 16 + 2 * NV;

  const float scale = 0.044194173824159216f;  // 1/sqrt(512)
  const bf16_t* kbase = k + ((size_t)b * 4096 + kv0) * 512;
  const bf16_t* vbase = vT + ((size_t)b * 512) * 4096 + kv0;

  // stage slice u into SB[buf]; exactly 4 gload_lds16 per thread (512 thr).
  auto stage_slice = [&](int u, int buf) {
    if (u < 16) {
      // K-slice [512kv x 32d], double-XOR swizzled
#pragma unroll
      for (int rnd = 0; rnd < 4; rnd++) {
        const int ch = rnd * 512 + tid;
        const int g4 = ch >> 4;
        const int w16 = ch & 15;
        const int cg = (w16 >> 2) ^ (g4 & 3);
        const int row = g4 * 4 + (w16 & 3);
        gload_lds16(kbase + (size_t)row * 512 + u * 32 + cg * 8,
                    &SB[buf][ch * 8]);
      }
    } else {
      const int v = u - 16;
      const int dh = (v >= NV) ? 1 : 0;
      const int kvt = v - dh * NV;
      const bf16_t* vb = vbase + (size_t)(dh * 256) * 4096;
      // V^T-slice [256d x 64kv], XOR swizzled
#pragma unroll
      for (int rnd = 0; rnd < 4; rnd++) {
        const int ch = rnd * 512 + tid;
        const int d = ch >> 3;
        const int cg = (ch & 7) ^ (d & 7);
        gload_lds16(vb + (size_t)d * 4096 + kvt * 64 + cg * 8, &SB[buf][ch * 8]);
      }
    }
  };

  // ---- prologue: slices 0,1 in flight (order pinned); Q frags after ------
  stage_slice(0, 0);
  ORDER_FENCE();
  stage_slice(1, 1);
  ORDER_FENCE();

  // Q B-frags: qf[kt] = Q[qrow=l15][kt*32 + quad*8 .. +7]
  bf16x8 qf[16];
  {
    const bf16_t* qp = q + ((size_t)(b * 4096 + t0w + l15)) * 512 + quad * 8;
#pragma unroll
    for (int kk = 0; kk < 16; kk++) qf[kk] = *(const bf16x8*)(qp + kk * 32);
  }

  // ---- Phase 1: S^T accumulate -------------------------------------------
  f32x4 Sacc[32];
#pragma unroll
  for (int m = 0; m < 32; m++) Sacc[m] = f32x4{0.f, 0.f, 0.f, 0.f};

  // per-lane A-frag base (elements); m-stride = 512 elements.
  const int abase =
      ((l15 >> 2) * 16 + (quad ^ ((l15 >> 2) & 3)) * 4 + (l15 & 3)) * 8;

  int cur = 0;
#pragma unroll
  for (int kt = 0; kt < 16; kt++) {
    asm volatile("s_waitcnt vmcnt(4)" ::: "memory");  // slice kt landed
    __builtin_amdgcn_sched_barrier(0);
    __builtin_amdgcn_s_barrier();
    const bf16_t* sb = &SB[cur][0];
#pragma unroll
    for (int m = 0; m < 32; m++) {
      if (m <= mmax) {  // wave-uniform
        const bf16x8 kf = *(const bf16x8*)(sb + abase + m * 512);
        Sacc[m] = MFMA_BF16(kf, qf[kt], Sacc[m]);
      }
    }
    asm volatile("s_waitcnt lgkmcnt(0)" ::: "memory");  // my reads done
    __builtin_amdgcn_sched_barrier(0);
    __builtin_amdgcn_s_barrier();
    stage_slice(kt + 2, cur);  // overwrite just-computed buffer (kt+2 <= 17)
    cur ^= 1;
  }

  // ---- Phase 2: masked softmax (overlaps V slices 16,17 in flight) -------
  const int qr = t0w + l15;
  float mx = NEG_BIG;
#pragma unroll
  for (int m = 0; m < 32; m++) {
    if (m <= mmax) {
#pragma unroll
      for (int r = 0; r < 4; r++) {
        const int kv = kv0 + m * 16 + quad * 4 + r;
        const float vvv = (kv <= qr) ? Sacc[m][r] : NEG_BIG;
        Sacc[m][r] = vvv;
        mx = fmaxf(mx, vvv);
      }
    }
  }
  mx = fmaxf(mx, __shfl_xor(mx, 16));
  mx = fmaxf(mx, __shfl_xor(mx, 32));  // finite: kv0 <= qr always

  float lrow = 0.0f;
  bf16x4 pb[32];
#pragma unroll
  for (int m = 0; m < 32; m++) {
    bf16x4 pv = {};
    if (m <= mmax) {
#pragma unroll
      for (int r = 0; r < 4; r++) {
        const float p = __expf((Sacc[m][r] - mx) * scale);  // masked -> 0
        pv[r] = (bf16_t)p;
        lrow += p;
      }
    }
    pb[m] = pv;
  }
  lrow += __shfl_xor(lrow, 16);
  lrow += __shfl_xor(lrow, 32);

  if (quad == 0)
    stats[((size_t)wlocal * 4 + b) * 64 + wid4 * 16 + l15] =
        make_float2(mx * scale, lrow);

  // ---- Phase 3: O = P.V, both 256-d halves, unrolled kvt (rule #20) ------
  const int l64 = l15 * 64;
  const int qh = quad >> 1;
  const int ql = (quad & 1) * 4;
  const int s7 = l15 & 7;

#pragma unroll
  for (int dh = 0; dh < 2; dh++) {
    f32x4 Oacc[16];
#pragma unroll
    for (int dt = 0; dt < 16; dt++) Oacc[dt] = f32x4{0.f, 0.f, 0.f, 0.f};

#pragma unroll
    for (int kvt = 0; kvt < 8; kvt++) {
      if (kvt < NV) {  // block-uniform
        const int u = 16 + dh * NV + kvt;
        if (u < NSLICE - 1)
          asm volatile("s_waitcnt vmcnt(4)" ::: "memory");
        else
          asm volatile("s_waitcnt vmcnt(0)" ::: "memory");
        __builtin_amdgcn_sched_barrier(0);
        __builtin_amdgcn_s_barrier();
        if (kvt <= kvtmax) {  // wave-uniform
          const bf16_t* sb = &SB[cur][0];
#pragma unroll
          for (int dt = 0; dt < 16; dt++) {
#pragma unroll
            for (int gg = 0; gg < 4; gg++) {
              const bf16x4 vf = *(const bf16x4*)(
                  sb + dt * 1024 + l64 + (((gg * 2 + qh) ^ s7) << 3) + ql);
              Oacc[dt] = mfma16(pb[kvt * 4 + gg], vf, Oacc[dt]);
            }
          }
        }
        // epilogue on last live kvt: coalesced native-layout stores
        if (kvt == NV - 1) {
          bf16_t* pbase =
              partO + (size_t)obid * 32768 + dh * 16384 + wid4 * 4096;
#pragma unroll
          for (int dt = 0; dt < 16; dt++) {
            bf16x4 ov;
#pragma unroll
            for (int r = 0; r < 4; r++) ov[r] = (bf16_t)Oacc[dt][r];
            *(bf16x4*)(pbase + dt * 256 + l15 * 16 + quad * 4) = ov;
          }
        }
        asm volatile("s_waitcnt lgkmcnt(0)" ::: "memory");
        __builtin_amdgcn_sched_barrier(0);
        __builtin_amdgcn_s_barrier();
        if (u + 2 < NSLICE) stage_slice(u + 2, cur);
        cur ^= 1;
      }
    }
  }
}

// ---------------------------------------------------------------------------
// Stage 2: combine chunk partials per (b, s64, dh). Grid 512 (dh-split:
// 2 blocks/CU, half the per-block serial read chain). Reads partO native
// layout coalesced, normalizes in registers, transposes through a
// row-XOR-swizzled 32 KB LDS bounce, writes coalesced bf16x8 rows.
// ---------------------------------------------------------------------------
__global__ __launch_bounds__(256) void attn_combine_kernel(
    const bf16_t* __restrict__ partO, const float2* __restrict__ stats,
    bf16_t* __restrict__ o) {
  const int b = blockIdx.x & 3;
  const int s = (blockIdx.x >> 2) & 63;
  const int dh = blockIdx.x >> 8;
  const int g = s >> 3;
  const int nc = g + 1;
  const int w0 = 4 * g * (g + 1) + (s & 7) * (g + 1);

  __shared__ float wgt[8][64];
  __shared__ float linv[64];
  __shared__ bf16_t TB[64 * 256];  // 32 KB transpose bounce

  const int tid = threadIdx.x;
  if (tid < 64) {
    float mc[8], lc[8];
    float M = NEG_BIG;
    for (int cc = 0; cc < nc; cc++) {
      const float2 ml = stats[((size_t)(w0 + cc) * 4 + b) * 64 + tid];
      mc[cc] = ml.x;
      lc[cc] = ml.y;
      M = fmaxf(M, ml.x);
    }
    float L = 0.0f;
    for (int cc = 0; cc < nc; cc++) {
      const float wv = __expf(mc[cc] - M);
      wgt[cc][tid] = wv;
      L += wv * lc[cc];
    }
    linv[tid] = (L > 0.0f) ? 1.0f / L : 0.0f;
  }
  __syncthreads();

  // thread decode matching native layout: q-rows q0..q0+3, d = dt*16 + l15
  const int quad = tid & 3;
  const int l15 = (tid >> 2) & 15;
  const int wid = tid >> 6;
  const int q0 = wid * 16 + quad * 4;
  const f32x4 li4 = *(const f32x4*)(&linv[q0]);

  f32x4 acc4[16] = {};
  for (int cc = 0; cc < nc; cc++) {
    const bf16_t* pp = partO + (size_t)(((w0 + cc) << 2) | b) * 32768 +
                       dh * 16384 + wid * 4096 + l15 * 16 + quad * 4;
    const f32x4 wv4 = *(const f32x4*)(&wgt[cc][q0]);
#pragma unroll
    for (int dt = 0; dt < 16; dt++) {
      const bf16x4 p = *(const bf16x4*)(pp + dt * 256);
#pragma unroll
      for (int e = 0; e < 4; e++) acc4[dt][e] += wv4[e] * (float)p[e];
    }
  }
  // normalize + swizzled bounce write ([64 q][256 d] bf16, row XOR)
#pragma unroll
  for (int dt = 0; dt < 16; dt++) {
    const int d2 = (dt * 16 + l15) * 2;
#pragma unroll
    for (int r = 0; r < 4; r++) {
      const int qq = q0 + r;
      *(bf16_t*)((char*)TB + qq * 512 + (d2 ^ ((qq & 7) << 4))) =
          (bf16_t)(acc4[dt][r] * li4[r]);
    }
  }
  __syncthreads();
  // coalesced read + store
  const int row = tid >> 2;
  const int quarter = tid & 3;
  bf16_t* orow =
      o + ((size_t)(b * 4096 + s * 64 + row)) * 512 + dh * 256 + quarter * 64;
#pragma unroll
  for (int j = 0; j < 8; j++) {
    const int byte = row * 512 + ((quarter * 128 + j * 16) ^ ((row & 7) << 4));
    *(bf16x8*)(orow + j * 8) = *(const bf16x8*)((const char*)TB + byte);
  }
}

// ---------------------------------------------------------------------------
extern "C" void kernel_launch(void* const* d_in, const int* in_sizes, int n_in,
                              void* d_out, int out_size, void* d_ws, size_t ws_size,
                              hipStream_t stream) {
  const float* x_f = (const float*)d_in[0];   // [4,4096,512] fp32
  const float* wq_f = (const float*)d_in[1];  // [1536,512]   fp32
  const float* wp_f = (const float*)d_in[2];  // [512,512]    fp32
  float* out = (float*)d_out;                 // [4,4096,512] fp32

  // ws (bf16 unless noted): xb | wqb | wpb | q | k | vT | partO | stats
  bf16_t* xb = (bf16_t*)d_ws;                      // 16 MB (attn output)
  bf16_t* wqb = xb + (size_t)16384 * 512;          // 1.5 MB
  bf16_t* wpb = wqb + (size_t)1536 * 512;          // 0.5 MB
  bf16_t* q = wpb + (size_t)512 * 512;             // 16 MB
  bf16_t* kk = q + (size_t)16384 * 512;            // 16 MB
  bf16_t* vT = kk + (size_t)16384 * 512;           // 16 MB
  bf16_t* partO = vT + (size_t)16384 * 512;        // 1152*32768*2 = 75.5 MB
  float2* stats = (float2*)(partO + (size_t)1152 * 32768);  // 0.6 MB

  // 0) convert fp32 inputs -> bf16 (single launch)
  cvt3_kernel<<<9216, 256, 0, stream>>>(x_f, wq_f, wp_f, xb, wqb, wpb);

  // 1) qkv = x @ Wqkv^T ; v stored transposed (coalesced bounce epilogue)
  gemm_bt_kernel<0><<<128 * 12, 256, 0, stream>>>(xb, wqb, q, kk, vT, nullptr);
  // 2a) attention partials (QBLK=128, 8-wave slice sharing, XCD pinning)
  attn_part_kernel<<<576, 512, 0, stream>>>(q, kk, vT, partO, stats);
  // 2b) combine partials -> xb (dh-split grid)
  attn_combine_kernel<<<512, 256, 0, stream>>>(partO, stats, xb);
  // 3) y = attn @ Wproj^T -> fp32 d_out
  gemm_bt_kernel<1><<<128 * 4, 256, 0, stream>>>(xb, wpb, nullptr, nullptr, nullptr, out);
}

// Round 11
// 378.449 us; speedup vs baseline: 1.2569x; 1.0103x over previous
//
#include <hip/hip_runtime.h>
#include <hip/hip_bf16.h>
#include <stdint.h>

typedef __bf16 bf16_t;
typedef __bf16 bf16x4 __attribute__((ext_vector_type(4)));
typedef __bf16 bf16x8 __attribute__((ext_vector_type(8)));
typedef short s16x4 __attribute__((ext_vector_type(4)));
typedef float f32x4 __attribute__((ext_vector_type(4)));

static_assert(sizeof(bf16x8) == 16, "bf16x8 must be 16B");

#define MFMA_BF16(a, b, c) __builtin_amdgcn_mfma_f32_16x16x32_bf16((a), (b), (c), 0, 0, 0)

// 16x16x16 bf16 MFMA (A[m=l15][k=quad*4+i], B[k=quad*4+i][n=l15],
// C/D row=quad*4+r col=l15)
__device__ __forceinline__ f32x4 mfma16(bf16x4 a, bf16x4 b, f32x4 c) {
#if __has_builtin(__builtin_amdgcn_mfma_f32_16x16x16bf16_1k)
  union { bf16x4 h; s16x4 s; } ua, ub;
  ua.h = a;
  ub.h = b;
  return __builtin_amdgcn_mfma_f32_16x16x16bf16_1k(ua.s, ub.s, c, 0, 0, 0);
#else
  f32x4 d = c;
  asm volatile("v_mfma_f32_16x16x16_bf16 %0, %1, %2, %0" : "+v"(d) : "v"(a), "v"(b));
  return d;
#endif
}

typedef const __attribute__((address_space(1))) void* gas_ptr;
typedef __attribute__((address_space(3))) void* las_ptr;

__device__ __forceinline__ void gload_lds16(const void* g, void* l) {
  __builtin_amdgcn_global_load_lds((gas_ptr)g, (las_ptr)l, 16, 0, 0);
}

// compile-time memory-op ordering fence (pins global_load_lds issue order)
#define ORDER_FENCE() asm volatile("" ::: "memory")

#define NEG_BIG (-1.0e30f)

// ---------------------------------------------------------------------------
// fp32 -> bf16 convert, all three inputs in one launch.
// ---------------------------------------------------------------------------
__global__ __launch_bounds__(256) void cvt3_kernel(
    const float* __restrict__ x, const float* __restrict__ wq,
    const float* __restrict__ wp, bf16_t* __restrict__ xb,
    bf16_t* __restrict__ wqb, bf16_t* __restrict__ wpb) {
  const int i = (blockIdx.x * 256 + threadIdx.x) * 4;
  const float* src;
  bf16_t* dst;
  int off;
  if (i < 8388608) {
    src = x; dst = xb; off = 0;
  } else if (i < 9175040) {
    src = wq; dst = wqb; off = 8388608;
  } else {
    src = wp; dst = wpb; off = 9175040;
  }
  const f32x4 v = *(const f32x4*)(src + (i - off));
  bf16x4 o;
  o[0] = (bf16_t)v[0];
  o[1] = (bf16_t)v[1];
  o[2] = (bf16_t)v[2];
  o[3] = (bf16_t)v[3];
  *(bf16x4*)(dst + (i - off)) = o;
}

// ---------------------------------------------------------------------------
// GEMM (m97 structure): D[m][n] = sum_k A[m][k] * Bw[n][k]
// MODE 0: qkv -> q / k row-major, v transposed to vT[b][d][t];
//   LDS-bounce coalesced epilogue (R9: +30 us end-to-end).
// MODE 1: final epilogue -> o_f as FP32.
// ---------------------------------------------------------------------------
template <int MODE>
__global__ __launch_bounds__(256, 2) void gemm_bt_kernel(
    const bf16_t* __restrict__ A, const bf16_t* __restrict__ Bw,
    bf16_t* __restrict__ o_q, bf16_t* __restrict__ o_k, bf16_t* __restrict__ o_vT,
    float* __restrict__ o_f) {
  constexpr int K = 512;
  __shared__ bf16_t AB[2 * 128 * 32];  // As | Bs ; reused as 16-KB bounce tile
  bf16_t* As = AB;
  bf16_t* Bs = AB + 128 * 32;

  const int tid = threadIdx.x;
  const int lane = tid & 63;
  const int wid = tid >> 6;
  const int quad = lane >> 4;
  const int l15 = lane & 15;
  const int wm = wid >> 1;
  const int wn = wid & 1;

  const int mt = blockIdx.x & 127;
  const int nt = blockIdx.x >> 7;
  const int row0 = mt * 128;
  const int col0 = nt * 128;

  f32x4 acc[4][4] = {};

  for (int kt = 0; kt < K; kt += 32) {
    __syncthreads();
#pragma unroll
    for (int rnd = 0; rnd < 2; rnd++) {
      const int e = (rnd * 256 + tid) * 8;
      const int r = e >> 5;
      const int c = e & 31;
      gload_lds16(A + (size_t)(row0 + r) * K + kt + c, As + e);
      gload_lds16(Bw + (size_t)(col0 + r) * K + kt + c, Bs + e);
    }
    __syncthreads();

    bf16x8 af[4], bfr[4];
#pragma unroll
    for (int i = 0; i < 4; i++)
      af[i] = *(const bf16x8*)(As + (wm * 64 + i * 16 + l15) * 32 + quad * 8);
#pragma unroll
    for (int i = 0; i < 4; i++)
      bfr[i] = *(const bf16x8*)(Bs + (wn * 64 + i * 16 + l15) * 32 + quad * 8);
#pragma unroll
    for (int mi = 0; mi < 4; mi++)
#pragma unroll
      for (int ni = 0; ni < 4; ni++)
        acc[mi][ni] = MFMA_BF16(af[mi], bfr[ni], acc[mi][ni]);
  }

  if constexpr (MODE == 1) {
#pragma unroll
    for (int mi = 0; mi < 4; mi++) {
      const int row = row0 + wm * 64 + mi * 16 + quad * 4;
#pragma unroll
      for (int ni = 0; ni < 4; ni++) {
        const int col = col0 + wn * 64 + ni * 16 + l15;
#pragma unroll
        for (int r = 0; r < 4; r++)
          o_f[(size_t)(row + r) * 512 + col] = acc[mi][ni][r];
      }
    }
  } else {
    // ---- LDS-bounce coalesced epilogue (two 64-col halves) ----------------
    const bool isv = (nt >= 8);
    bf16_t* T = AB;  // 8192 bf16 = 16 KB
    __syncthreads();  // As/Bs dead
#pragma unroll
    for (int hh = 0; hh < 2; hh++) {
      if (wn == hh) {
        if (isv) {
          // tile [64 d][128 t], t XOR (d&15)<<3, vector bf16x4 writes
#pragma unroll
          for (int mi = 0; mi < 4; mi++)
#pragma unroll
            for (int ni = 0; ni < 4; ni++) {
              const int d_rel = ni * 16 + l15;
              const int trow = wm * 64 + mi * 16 + quad * 4;
              bf16x4 ov;
#pragma unroll
              for (int r = 0; r < 4; r++) ov[r] = (bf16_t)acc[mi][ni][r];
              *(bf16x4*)(T + d_rel * 128 + (trow ^ ((d_rel & 15) << 3))) = ov;
            }
        } else {
          // tile [128 t][64 d], d XOR (trow&7)<<3, scalar writes
#pragma unroll
          for (int mi = 0; mi < 4; mi++)
#pragma unroll
            for (int ni = 0; ni < 4; ni++)
#pragma unroll
              for (int r = 0; r < 4; r++) {
                const int d_rel = ni * 16 + l15;
                const int trow = wm * 64 + mi * 16 + quad * 4 + r;
                T[trow * 64 + (d_rel ^ ((trow & 7) << 3))] =
                    (bf16_t)acc[mi][ni][r];
              }
        }
      }
      __syncthreads();
      if (isv) {
        // 8 lanes x 16 B = full 128-B contiguous vT row runs
        const int bb = row0 >> 12;
        const int t0 = row0 & 4095;
#pragma unroll
        for (int p = 0; p < 2; p++) {
          const int d = p * 32 + (tid >> 3);
          bf16_t* vrow =
              o_vT + ((size_t)(bb * 512 + col0 - 1024 + hh * 64 + d)) * 4096 + t0;
#pragma unroll
          for (int j = 0; j < 2; j++) {
            const int t8 = (tid & 7) * 8 + j * 64;
            *(bf16x8*)(vrow + t8) =
                *(const bf16x8*)(T + d * 128 + (t8 ^ ((d & 15) << 3)));
          }
        }
      } else {
        bf16_t* dstp = (nt < 4) ? o_q : o_k;
        const int cbase = col0 - ((nt < 4) ? 0 : 512) + hh * 64;
#pragma unroll
        for (int p = 0; p < 2; p++) {
          const int rrow = p * 64 + (tid >> 2);
          bf16_t* drow = dstp + (size_t)(row0 + rrow) * 512 + cbase;
#pragma unroll
          for (int j = 0; j < 2; j++) {
            const int c8 = (tid & 3) * 8 + j * 32;
            *(bf16x8*)(drow + c8) =
                *(const bf16x8*)(T + rrow * 64 + (c8 ^ ((rrow & 7) << 3)));
          }
        }
      }
      __syncthreads();  // T reused for next half
    }
  }
}

// ---------------------------------------------------------------------------
// Split-KV flash attention stage 1 — TRIPLE-BUFFER, SINGLE-BARRIER pipeline.
// QBLK=128, 512 threads / 8 waves, XCD-pinned (R10 decode). 3 x 32 KB LDS.
// Per slice u: { vmcnt(4); s_barrier; stage(u+2)->buf[(u+2)%3]; compute
// buf[u%3] }. Safety: buf[(u+2)%3] was computed at u-1; any wave past
// barrier u has consumed its u-1 ds_reads (MFMAs consuming them issue
// before the barrier, in-order issue). Halves barrier count vs R10 (34->~22
// per block incl. tail) and removes ALL lgkmcnt(0) drains; stage issues
// BEFORE compute so loads get ~2 compute phases of latency cover.
// Outputs land in legacy 64-row (w, b) partO slots; combine unchanged.
// ---------------------------------------------------------------------------
__global__ __launch_bounds__(512, 2) void attn_part_kernel(
    const bf16_t* __restrict__ q, const bf16_t* __restrict__ k,
    const bf16_t* __restrict__ vT, bf16_t* __restrict__ partO,
    float2* __restrict__ stats) {
  __shared__ bf16_t SB[3][16384];  // 3 x 32 KB triple buffer

  const int tid = threadIdx.x;
  const int lane = tid & 63;
  const int wid = tid >> 6;   // 0..7
  const int quad = lane >> 4;
  const int l15 = lane & 15;

  // ---- decode: bid -> (b, s, c); (b,c) groups pinned per XCD --------------
  const int x = blockIdx.x & 7;   // XCD (round-robin)
  const int n = blockIdx.x >> 3;  // 0..71 within XCD
  const int b = x >> 1;
  int c, i;
  if ((x & 1) == 0) {             // c in {0,3,5,6}: sizes 32,20,12,8
    if (n < 32)      { c = 0; i = n; }
    else if (n < 52) { c = 3; i = n - 32; }
    else if (n < 64) { c = 5; i = n - 52; }
    else             { c = 6; i = n - 64; }
  } else {                        // c in {1,2,4,7}: sizes 28,24,16,4
    if (n < 28)      { c = 1; i = n; }
    else if (n < 52) { c = 2; i = n - 28; }
    else if (n < 68) { c = 4; i = n - 52; }
    else             { c = 7; i = n - 68; }
  }
  const int s = 4 * c + i;        // strip 0..31 (128 q rows); s >= 4c

  // legacy 64-row-strip indices for the two half-strips
  const int g = s >> 2;                         // = (2s)>>3 = (2s+1)>>3
  const int wA = 4 * g * (g + 1) + ((2 * s) & 7) * (g + 1) + c;
  const int wlocal = (wid < 4) ? wA : wA + (g + 1);
  const int obid = (wlocal << 2) | b;
  const int wid4 = wid & 3;

  const int t0w = s * 128 + wid * 16;  // this wave's q rows
  const int kv0 = c * 512;
  const int mmax = min(31, (t0w + 15 - kv0) >> 4);           // wave-uniform
  const int kvtmax = mmax >> 2;                              // wave-uniform
  const int mmax_blk = min(31, (s * 128 + 127 - kv0) >> 4);  // block-uniform
  const int NV = (mmax_blk >> 2) + 1;                        // V slices/half, >=2
  const int NSLICE = 16 + 2 * NV;                            // >= 20

  const float scale = 0.044194173824159216f;  // 1/sqrt(512)
  const bf16_t* kbase = k + ((size_t)b * 4096 + kv0) * 512;
  const bf16_t* vbase = vT + ((size_t)b * 512) * 4096 + kv0;

  // stage slice u into SB[buf]; exactly 4 gload_lds16 per thread (512 thr).
  auto stage_slice = [&](int u, int buf) {
    if (u < 16) {
      // K-slice [512kv x 32d], double-XOR swizzled
#pragma unroll
      for (int rnd = 0; rnd < 4; rnd++) {
        const int ch = rnd * 512 + tid;
        const int g4 = ch >> 4;
        const int w16 = ch & 15;
        const int cg = (w16 >> 2) ^ (g4 & 3);
        const int row = g4 * 4 + (w16 & 3);
        gload_lds16(kbase + (size_t)row * 512 + u * 32 + cg * 8,
                    &SB[buf][ch * 8]);
      }
    } else {
      const int v = u - 16;
      const int dh = (v >= NV) ? 1 : 0;
      const int kvt = v - dh * NV;
      const bf16_t* vb = vbase + (size_t)(dh * 256) * 4096;
      // V^T-slice [256d x 64kv], XOR swizzled
#pragma unroll
      for (int rnd = 0; rnd < 4; rnd++) {
        const int ch = rnd * 512 + tid;
        const int d = ch >> 3;
        const int cg = (ch & 7) ^ (d & 7);
        gload_lds16(vb + (size_t)d * 4096 + kvt * 64 + cg * 8, &SB[buf][ch * 8]);
      }
    }
  };

  // ---- prologue: slices 0,1 in flight (order pinned); Q frags after ------
  stage_slice(0, 0);
  ORDER_FENCE();
  stage_slice(1, 1);
  ORDER_FENCE();

  // Q B-frags: qf[kt] = Q[qrow=l15][kt*32 + quad*8 .. +7]
  bf16x8 qf[16];
  {
    const bf16_t* qp = q + ((size_t)(b * 4096 + t0w + l15)) * 512 + quad * 8;
#pragma unroll
    for (int kk = 0; kk < 16; kk++) qf[kk] = *(const bf16x8*)(qp + kk * 32);
  }

  // ---- Phase 1: S^T accumulate -------------------------------------------
  f32x4 Sacc[32];
#pragma unroll
  for (int m = 0; m < 32; m++) Sacc[m] = f32x4{0.f, 0.f, 0.f, 0.f};

  // per-lane A-frag base (elements); m-stride = 512 elements.
  const int abase =
      ((l15 >> 2) * 16 + (quad ^ ((l15 >> 2) & 3)) * 4 + (l15 & 3)) * 8;

#pragma unroll
  for (int kt = 0; kt < 16; kt++) {
    asm volatile("s_waitcnt vmcnt(4)" ::: "memory");  // slice kt landed (mine)
    __builtin_amdgcn_sched_barrier(0);
    __builtin_amdgcn_s_barrier();                     // all waves' parts landed
    __builtin_amdgcn_sched_barrier(0);
    stage_slice(kt + 2, (kt + 2) % 3);  // kt+2 <= 17 < NSLICE always
    const bf16_t* sb = &SB[kt % 3][0];
#pragma unroll
    for (int m = 0; m < 32; m++) {
      if (m <= mmax) {  // wave-uniform
        const bf16x8 kf = *(const bf16x8*)(sb + abase + m * 512);
        Sacc[m] = MFMA_BF16(kf, qf[kt], Sacc[m]);
      }
    }
  }

  // ---- Phase 2: masked softmax (V slices 16,17 in flight) ----------------
  const int qr = t0w + l15;
  float mx = NEG_BIG;
#pragma unroll
  for (int m = 0; m < 32; m++) {
    if (m <= mmax) {
#pragma unroll
      for (int r = 0; r < 4; r++) {
        const int kv = kv0 + m * 16 + quad * 4 + r;
        const float vvv = (kv <= qr) ? Sacc[m][r] : NEG_BIG;
        Sacc[m][r] = vvv;
        mx = fmaxf(mx, vvv);
      }
    }
  }
  mx = fmaxf(mx, __shfl_xor(mx, 16));
  mx = fmaxf(mx, __shfl_xor(mx, 32));  // finite: kv0 <= qr always

  float lrow = 0.0f;
  bf16x4 pb[32];
#pragma unroll
  for (int m = 0; m < 32; m++) {
    bf16x4 pv = {};
    if (m <= mmax) {
#pragma unroll
      for (int r = 0; r < 4; r++) {
        const float p = __expf((Sacc[m][r] - mx) * scale);  // masked -> 0
        pv[r] = (bf16_t)p;
        lrow += p;
      }
    }
    pb[m] = pv;
  }
  lrow += __shfl_xor(lrow, 16);
  lrow += __shfl_xor(lrow, 32);

  if (quad == 0)
    stats[((size_t)wlocal * 4 + b) * 64 + wid4 * 16 + l15] =
        make_float2(mx * scale, lrow);

  // ---- Phase 3: O = P.V, both 256-d halves, unrolled kvt (rule #20) ------
  const int l64 = l15 * 64;
  const int qh = quad >> 1;
  const int ql = (quad & 1) * 4;
  const int s7 = l15 & 7;

#pragma unroll
  for (int dh = 0; dh < 2; dh++) {
    f32x4 Oacc[16];
#pragma unroll
    for (int dt = 0; dt < 16; dt++) Oacc[dt] = f32x4{0.f, 0.f, 0.f, 0.f};

#pragma unroll
    for (int kvt = 0; kvt < 8; kvt++) {
      if (kvt < NV) {  // block-uniform
        const int u = 16 + dh * NV + kvt;
        if (u < NSLICE - 1)
          asm volatile("s_waitcnt vmcnt(4)" ::: "memory");
        else
          asm volatile("s_waitcnt vmcnt(0)" ::: "memory");
        __builtin_amdgcn_sched_barrier(0);
        __builtin_amdgcn_s_barrier();
        __builtin_amdgcn_sched_barrier(0);
        if (u + 2 < NSLICE) stage_slice(u + 2, (u + 2) % 3);
        if (kvt <= kvtmax) {  // wave-uniform
          const bf16_t* sb = &SB[u % 3][0];
#pragma unroll
          for (int dt = 0; dt < 16; dt++) {
#pragma unroll
            for (int gg = 0; gg < 4; gg++) {
              const bf16x4 vf = *(const bf16x4*)(
                  sb + dt * 1024 + l64 + (((gg * 2 + qh) ^ s7) << 3) + ql);
              Oacc[dt] = mfma16(pb[kvt * 4 + gg], vf, Oacc[dt]);
            }
          }
        }
        // epilogue on last live kvt: coalesced native-layout stores
        if (kvt == NV - 1) {
          bf16_t* pbase =
              partO + (size_t)obid * 32768 + dh * 16384 + wid4 * 4096;
#pragma unroll
          for (int dt = 0; dt < 16; dt++) {
            bf16x4 ov;
#pragma unroll
            for (int r = 0; r < 4; r++) ov[r] = (bf16_t)Oacc[dt][r];
            *(bf16x4*)(pbase + dt * 256 + l15 * 16 + quad * 4) = ov;
          }
        }
      }
    }
  }
}

// ---------------------------------------------------------------------------
// Stage 2: combine chunk partials per (b, s64, dh). Grid 512 (dh-split).
// Reads partO native layout coalesced, normalizes in registers, transposes
// through a row-XOR-swizzled 32 KB LDS bounce, writes coalesced bf16x8 rows.
// ---------------------------------------------------------------------------
__global__ __launch_bounds__(256) void attn_combine_kernel(
    const bf16_t* __restrict__ partO, const float2* __restrict__ stats,
    bf16_t* __restrict__ o) {
  const int b = blockIdx.x & 3;
  const int s = (blockIdx.x >> 2) & 63;
  const int dh = blockIdx.x >> 8;
  const int g = s >> 3;
  const int nc = g + 1;
  const int w0 = 4 * g * (g + 1) + (s & 7) * (g + 1);

  __shared__ float wgt[8][64];
  __shared__ float linv[64];
  __shared__ bf16_t TB[64 * 256];  // 32 KB transpose bounce

  const int tid = threadIdx.x;
  if (tid < 64) {
    float mc[8], lc[8];
    float M = NEG_BIG;
    for (int cc = 0; cc < nc; cc++) {
      const float2 ml = stats[((size_t)(w0 + cc) * 4 + b) * 64 + tid];
      mc[cc] = ml.x;
      lc[cc] = ml.y;
      M = fmaxf(M, ml.x);
    }
    float L = 0.0f;
    for (int cc = 0; cc < nc; cc++) {
      const float wv = __expf(mc[cc] - M);
      wgt[cc][tid] = wv;
      L += wv * lc[cc];
    }
    linv[tid] = (L > 0.0f) ? 1.0f / L : 0.0f;
  }
  __syncthreads();

  // thread decode matching native layout: q-rows q0..q0+3, d = dt*16 + l15
  const int quad = tid & 3;
  const int l15 = (tid >> 2) & 15;
  const int wid = tid >> 6;
  const int q0 = wid * 16 + quad * 4;
  const f32x4 li4 = *(const f32x4*)(&linv[q0]);

  f32x4 acc4[16] = {};
  for (int cc = 0; cc < nc; cc++) {
    const bf16_t* pp = partO + (size_t)(((w0 + cc) << 2) | b) * 32768 +
                       dh * 16384 + wid * 4096 + l15 * 16 + quad * 4;
    const f32x4 wv4 = *(const f32x4*)(&wgt[cc][q0]);
#pragma unroll
    for (int dt = 0; dt < 16; dt++) {
      const bf16x4 p = *(const bf16x4*)(pp + dt * 256);
#pragma unroll
      for (int e = 0; e < 4; e++) acc4[dt][e] += wv4[e] * (float)p[e];
    }
  }
  // normalize + swizzled bounce write ([64 q][256 d] bf16, row XOR)
#pragma unroll
  for (int dt = 0; dt < 16; dt++) {
    const int d2 = (dt * 16 + l15) * 2;
#pragma unroll
    for (int r = 0; r < 4; r++) {
      const int qq = q0 + r;
      *(bf16_t*)((char*)TB + qq * 512 + (d2 ^ ((qq & 7) << 4))) =
          (bf16_t)(acc4[dt][r] * li4[r]);
    }
  }
  __syncthreads();
  // coalesced read + store
  const int row = tid >> 2;
  const int quarter = tid & 3;
  bf16_t* orow =
      o + ((size_t)(b * 4096 + s * 64 + row)) * 512 + dh * 256 + quarter * 64;
#pragma unroll
  for (int j = 0; j < 8; j++) {
    const int byte = row * 512 + ((quarter * 128 + j * 16) ^ ((row & 7) << 4));
    *(bf16x8*)(orow + j * 8) = *(const bf16x8*)((const char*)TB + byte);
  }
}

// ---------------------------------------------------------------------------
extern "C" void kernel_launch(void* const* d_in, const int* in_sizes, int n_in,
                              void* d_out, int out_size, void* d_ws, size_t ws_size,
                              hipStream_t stream) {
  const float* x_f = (const float*)d_in[0];   // [4,4096,512] fp32
  const float* wq_f = (const float*)d_in[1];  // [1536,512]   fp32
  const float* wp_f = (const float*)d_in[2];  // [512,512]    fp32
  float* out = (float*)d_out;                 // [4,4096,512] fp32

  // ws (bf16 unless noted): xb | wqb | wpb | q | k | vT | partO | stats
  bf16_t* xb = (bf16_t*)d_ws;                      // 16 MB (attn output)
  bf16_t* wqb = xb + (size_t)16384 * 512;          // 1.5 MB
  bf16_t* wpb = wqb + (size_t)1536 * 512;          // 0.5 MB
  bf16_t* q = wpb + (size_t)512 * 512;             // 16 MB
  bf16_t* kk = q + (size_t)16384 * 512;            // 16 MB
  bf16_t* vT = kk + (size_t)16384 * 512;           // 16 MB
  bf16_t* partO = vT + (size_t)16384 * 512;        // 1152*32768*2 = 75.5 MB
  float2* stats = (float2*)(partO + (size_t)1152 * 32768);  // 0.6 MB

  // 0) convert fp32 inputs -> bf16 (single launch)
  cvt3_kernel<<<9216, 256, 0, stream>>>(x_f, wq_f, wp_f, xb, wqb, wpb);

  // 1) qkv = x @ Wqkv^T ; v stored transposed (coalesced bounce epilogue)
  gemm_bt_kernel<0><<<128 * 12, 256, 0, stream>>>(xb, wqb, q, kk, vT, nullptr);
  // 2a) attention partials (triple-buffer single-barrier, XCD pinning)
  attn_part_kernel<<<576, 512, 0, stream>>>(q, kk, vT, partO, stats);
  // 2b) combine partials -> xb (dh-split grid)
  attn_combine_kernel<<<512, 256, 0, stream>>>(partO, stats, xb);
  // 3) y = attn @ Wproj^T -> fp32 d_out
  gemm_bt_kernel<1><<<128 * 4, 256, 0, stream>>>(xb, wpb, nullptr, nullptr, nullptr, out);
}

// Round 12
// 366.545 us; speedup vs baseline: 1.2977x; 1.0325x over previous
//
#include <hip/hip_runtime.h>
#include <hip/hip_bf16.h>
#include <stdint.h>

typedef __bf16 bf16_t;
typedef __bf16 bf16x4 __attribute__((ext_vector_type(4)));
typedef __bf16 bf16x8 __attribute__((ext_vector_type(8)));
typedef short s16x4 __attribute__((ext_vector_type(4)));
typedef float f32x4 __attribute__((ext_vector_type(4)));

static_assert(sizeof(bf16x8) == 16, "bf16x8 must be 16B");

#define MFMA_BF16(a, b, c) __builtin_amdgcn_mfma_f32_16x16x32_bf16((a), (b), (c), 0, 0, 0)

// 16x16x16 bf16 MFMA (A[m=l15][k=quad*4+i], B[k=quad*4+i][n=l15],
// C/D row=quad*4+r col=l15)
__device__ __forceinline__ f32x4 mfma16(bf16x4 a, bf16x4 b, f32x4 c) {
#if __has_builtin(__builtin_amdgcn_mfma_f32_16x16x16bf16_1k)
  union { bf16x4 h; s16x4 s; } ua, ub;
  ua.h = a;
  ub.h = b;
  return __builtin_amdgcn_mfma_f32_16x16x16bf16_1k(ua.s, ub.s, c, 0, 0, 0);
#else
  f32x4 d = c;
  asm volatile("v_mfma_f32_16x16x16_bf16 %0, %1, %2, %0" : "+v"(d) : "v"(a), "v"(b));
  return d;
#endif
}

typedef const __attribute__((address_space(1))) void* gas_ptr;
typedef __attribute__((address_space(3))) void* las_ptr;

__device__ __forceinline__ void gload_lds16(const void* g, void* l) {
  __builtin_amdgcn_global_load_lds((gas_ptr)g, (las_ptr)l, 16, 0, 0);
}

// compile-time memory-op ordering fence (pins global_load_lds issue order)
#define ORDER_FENCE() asm volatile("" ::: "memory")

#define NEG_BIG (-1.0e30f)

// ---------------------------------------------------------------------------
// fp32 -> bf16 convert, all three inputs in one launch.
// ---------------------------------------------------------------------------
__global__ __launch_bounds__(256) void cvt3_kernel(
    const float* __restrict__ x, const float* __restrict__ wq,
    const float* __restrict__ wp, bf16_t* __restrict__ xb,
    bf16_t* __restrict__ wqb, bf16_t* __restrict__ wpb) {
  const int i = (blockIdx.x * 256 + threadIdx.x) * 4;
  const float* src;
  bf16_t* dst;
  int off;
  if (i < 8388608) {
    src = x; dst = xb; off = 0;
  } else if (i < 9175040) {
    src = wq; dst = wqb; off = 8388608;
  } else {
    src = wp; dst = wpb; off = 9175040;
  }
  const f32x4 v = *(const f32x4*)(src + (i - off));
  bf16x4 o;
  o[0] = (bf16_t)v[0];
  o[1] = (bf16_t)v[1];
  o[2] = (bf16_t)v[2];
  o[3] = (bf16_t)v[3];
  *(bf16x4*)(dst + (i - off)) = o;
}

// ---------------------------------------------------------------------------
// GEMM (m97 structure): D[m][n] = sum_k A[m][k] * Bw[n][k]
// A-panel XCD-locality decode: XCD x owns mt in [16x, 16x+16) for ALL nt ->
// each XCD's 2-MB A-panel is L2-resident, reused across nt panels.
// MODE 0 (grid 1536 = 8 x 16 x 12): qkv -> q/k row-major, v -> vT[b][d][t];
//   LDS-bounce coalesced epilogue.
// MODE 1 (grid 512 = 8 x 16 x 4): -> o_f as FP32.
// ---------------------------------------------------------------------------
template <int MODE>
__global__ __launch_bounds__(256, 2) void gemm_bt_kernel(
    const bf16_t* __restrict__ A, const bf16_t* __restrict__ Bw,
    bf16_t* __restrict__ o_q, bf16_t* __restrict__ o_k, bf16_t* __restrict__ o_vT,
    float* __restrict__ o_f) {
  constexpr int K = 512;
  __shared__ bf16_t AB[2 * 128 * 32];  // As | Bs ; reused as 16-KB bounce tile
  bf16_t* As = AB;
  bf16_t* Bs = AB + 128 * 32;

  const int tid = threadIdx.x;
  const int lane = tid & 63;
  const int wid = tid >> 6;
  const int quad = lane >> 4;
  const int l15 = lane & 15;
  const int wm = wid >> 1;
  const int wn = wid & 1;

  // XCD-locality decode: mt grouped per XCD, nt varies within the XCD.
  const int xx = blockIdx.x & 7;
  const int nn = blockIdx.x >> 3;
  const int mt = xx * 16 + (nn & 15);
  const int nt = nn >> 4;
  const int row0 = mt * 128;
  const int col0 = nt * 128;

  f32x4 acc[4][4] = {};

  for (int kt = 0; kt < K; kt += 32) {
    __syncthreads();
#pragma unroll
    for (int rnd = 0; rnd < 2; rnd++) {
      const int e = (rnd * 256 + tid) * 8;
      const int r = e >> 5;
      const int c = e & 31;
      gload_lds16(A + (size_t)(row0 + r) * K + kt + c, As + e);
      gload_lds16(Bw + (size_t)(col0 + r) * K + kt + c, Bs + e);
    }
    __syncthreads();

    bf16x8 af[4], bfr[4];
#pragma unroll
    for (int i = 0; i < 4; i++)
      af[i] = *(const bf16x8*)(As + (wm * 64 + i * 16 + l15) * 32 + quad * 8);
#pragma unroll
    for (int i = 0; i < 4; i++)
      bfr[i] = *(const bf16x8*)(Bs + (wn * 64 + i * 16 + l15) * 32 + quad * 8);
#pragma unroll
    for (int mi = 0; mi < 4; mi++)
#pragma unroll
      for (int ni = 0; ni < 4; ni++)
        acc[mi][ni] = MFMA_BF16(af[mi], bfr[ni], acc[mi][ni]);
  }

  if constexpr (MODE == 1) {
#pragma unroll
    for (int mi = 0; mi < 4; mi++) {
      const int row = row0 + wm * 64 + mi * 16 + quad * 4;
#pragma unroll
      for (int ni = 0; ni < 4; ni++) {
        const int col = col0 + wn * 64 + ni * 16 + l15;
#pragma unroll
        for (int r = 0; r < 4; r++)
          o_f[(size_t)(row + r) * 512 + col] = acc[mi][ni][r];
      }
    }
  } else {
    // ---- LDS-bounce coalesced epilogue (two 64-col halves) ----------------
    const bool isv = (nt >= 8);
    bf16_t* T = AB;  // 8192 bf16 = 16 KB
    __syncthreads();  // As/Bs dead
#pragma unroll
    for (int hh = 0; hh < 2; hh++) {
      if (wn == hh) {
        if (isv) {
          // tile [64 d][128 t], t XOR (d&15)<<3, vector bf16x4 writes
#pragma unroll
          for (int mi = 0; mi < 4; mi++)
#pragma unroll
            for (int ni = 0; ni < 4; ni++) {
              const int d_rel = ni * 16 + l15;
              const int trow = wm * 64 + mi * 16 + quad * 4;
              bf16x4 ov;
#pragma unroll
              for (int r = 0; r < 4; r++) ov[r] = (bf16_t)acc[mi][ni][r];
              *(bf16x4*)(T + d_rel * 128 + (trow ^ ((d_rel & 15) << 3))) = ov;
            }
        } else {
          // tile [128 t][64 d], d XOR (trow&7)<<3, scalar writes
#pragma unroll
          for (int mi = 0; mi < 4; mi++)
#pragma unroll
            for (int ni = 0; ni < 4; ni++)
#pragma unroll
              for (int r = 0; r < 4; r++) {
                const int d_rel = ni * 16 + l15;
                const int trow = wm * 64 + mi * 16 + quad * 4 + r;
                T[trow * 64 + (d_rel ^ ((trow & 7) << 3))] =
                    (bf16_t)acc[mi][ni][r];
              }
        }
      }
      __syncthreads();
      if (isv) {
        // 8 lanes x 16 B = full 128-B contiguous vT row runs
        const int bb = row0 >> 12;
        const int t0 = row0 & 4095;
#pragma unroll
        for (int p = 0; p < 2; p++) {
          const int d = p * 32 + (tid >> 3);
          bf16_t* vrow =
              o_vT + ((size_t)(bb * 512 + col0 - 1024 + hh * 64 + d)) * 4096 + t0;
#pragma unroll
          for (int j = 0; j < 2; j++) {
            const int t8 = (tid & 7) * 8 + j * 64;
            *(bf16x8*)(vrow + t8) =
                *(const bf16x8*)(T + d * 128 + (t8 ^ ((d & 15) << 3)));
          }
        }
      } else {
        bf16_t* dstp = (nt < 4) ? o_q : o_k;
        const int cbase = col0 - ((nt < 4) ? 0 : 512) + hh * 64;
#pragma unroll
        for (int p = 0; p < 2; p++) {
          const int rrow = p * 64 + (tid >> 2);
          bf16_t* drow = dstp + (size_t)(row0 + rrow) * 512 + cbase;
#pragma unroll
          for (int j = 0; j < 2; j++) {
            const int c8 = (tid & 3) * 8 + j * 32;
            *(bf16x8*)(drow + c8) =
                *(const bf16x8*)(T + rrow * 64 + (c8 ^ ((rrow & 7) << 3)));
          }
        }
      }
      __syncthreads();  // T reused for next half
    }
  }
}

// ---------------------------------------------------------------------------
// Split-KV flash attention stage 1 — R9 body (measured best 205 us):
// counted-vmcnt raw-barrier dbuf pipeline, QBLK=64, 256 threads, XCD pinning
// + LONGEST-FIRST intra-XCD order (block cost ~ min(8, i+1); reversed i puts
// cost-8 blocks first, short diagonal blocks last -> smaller scheduling tail).
// partO/stats keep legacy (w, b) indexing -> combine unchanged.
// ---------------------------------------------------------------------------
__global__ __launch_bounds__(256, 2) void attn_part_kernel(
    const bf16_t* __restrict__ q, const bf16_t* __restrict__ k,
    const bf16_t* __restrict__ vT, bf16_t* __restrict__ partO,
    float2* __restrict__ stats) {
  __shared__ bf16_t SB[2][16384];  // 2 x 32 KB double buffer

  const int tid = threadIdx.x;
  const int lane = tid & 63;
  const int wid = tid >> 6;
  const int quad = lane >> 4;
  const int l15 = lane & 15;

  // ---- decode: bid -> (b, s, c); (b,c) pinned per XCD; i REVERSED ---------
  const int x = blockIdx.x & 7;   // XCD (round-robin)
  const int n = blockIdx.x >> 3;  // 0..143 within XCD
  const int b = x >> 1;
  int c, i;
  if ((x & 1) == 0) {             // c in {0,2,4}: sizes 64,48,32
    if (n < 64)       { c = 0; i = 63 - n; }
    else if (n < 112) { c = 2; i = 111 - n; }
    else              { c = 4; i = 143 - n; }
  } else {                        // c in {1,3,5,6,7}: sizes 56,40,24,16,8
    if (n < 56)       { c = 1; i = 55 - n; }
    else if (n < 96)  { c = 3; i = 95 - n; }
    else if (n < 120) { c = 5; i = 119 - n; }
    else if (n < 136) { c = 6; i = 135 - n; }
    else              { c = 7; i = 143 - n; }
  }
  const int s = 8 * c + i;        // valid strips for chunk c are s >= 8c
  const int g = s >> 3;
  const int w = 4 * g * (g + 1) + (s & 7) * (g + 1) + c;  // legacy index
  const int obid = (w << 2) | b;                          // legacy partO slot

  const int t0w = s * 64 + wid * 16;  // this wave's q rows
  const int kv0 = c * 512;
  const int mmax = min(31, (t0w + 15 - kv0) >> 4);         // wave-uniform
  const int kvtmax = mmax >> 2;                            // wave-uniform
  const int mmax_blk = min(31, (s * 64 + 63 - kv0) >> 4);  // block-uniform
  const int NV = (mmax_blk >> 2) + 1;                      // V slices per half
  const int NSLICE = 16 + 2 * NV;                          // >= 18 always

  const float scale = 0.044194173824159216f;  // 1/sqrt(512)
  const bf16_t* kbase = k + ((size_t)b * 4096 + kv0) * 512;
  const bf16_t* vbase = vT + ((size_t)b * 512) * 4096 + kv0;

  // stage slice u into SB[buf]; exactly 8 gload_lds16 per thread.
  auto stage_slice = [&](int u, int buf) {
    if (u < 16) {
      // K-slice [512kv x 32d], double-XOR swizzled
#pragma unroll
      for (int rnd = 0; rnd < 8; rnd++) {
        const int ch = rnd * 256 + tid;
        const int g4 = ch >> 4;
        const int w16 = ch & 15;
        const int cg = (w16 >> 2) ^ (g4 & 3);
        const int row = g4 * 4 + (w16 & 3);
        gload_lds16(kbase + (size_t)row * 512 + u * 32 + cg * 8,
                    &SB[buf][ch * 8]);
      }
    } else {
      const int v = u - 16;
      const int dh = (v >= NV) ? 1 : 0;
      const int kvt = v - dh * NV;
      const bf16_t* vb = vbase + (size_t)(dh * 256) * 4096;
      // V^T-slice [256d x 64kv], XOR swizzled
#pragma unroll
      for (int rnd = 0; rnd < 8; rnd++) {
        const int ch = rnd * 256 + tid;
        const int d = ch >> 3;
        const int cg = (ch & 7) ^ (d & 7);
        gload_lds16(vb + (size_t)d * 4096 + kvt * 64 + cg * 8, &SB[buf][ch * 8]);
      }
    }
  };

  // ---- prologue: slices 0,1 in flight (order pinned); Q frags after ------
  stage_slice(0, 0);
  ORDER_FENCE();
  stage_slice(1, 1);
  ORDER_FENCE();

  // Q B-frags: qf[kt] = Q[qrow=l15][kt*32 + quad*8 .. +7]
  bf16x8 qf[16];
  {
    const bf16_t* qp = q + ((size_t)(b * 4096 + t0w + l15)) * 512 + quad * 8;
#pragma unroll
    for (int kk = 0; kk < 16; kk++) qf[kk] = *(const bf16x8*)(qp + kk * 32);
  }

  // ---- Phase 1: S^T accumulate -------------------------------------------
  f32x4 Sacc[32];
#pragma unroll
  for (int m = 0; m < 32; m++) Sacc[m] = f32x4{0.f, 0.f, 0.f, 0.f};

  // per-lane A-frag base (elements); m-stride = 512 elements.
  const int abase =
      ((l15 >> 2) * 16 + (quad ^ ((l15 >> 2) & 3)) * 4 + (l15 & 3)) * 8;

  int cur = 0;
#pragma unroll
  for (int kt = 0; kt < 16; kt++) {
    asm volatile("s_waitcnt vmcnt(8)" ::: "memory");  // slice kt landed
    __builtin_amdgcn_sched_barrier(0);
    __builtin_amdgcn_s_barrier();
    const bf16_t* sb = &SB[cur][0];
#pragma unroll
    for (int m = 0; m < 32; m++) {
      if (m <= mmax) {  // wave-uniform
        const bf16x8 kf = *(const bf16x8*)(sb + abase + m * 512);
        Sacc[m] = MFMA_BF16(kf, qf[kt], Sacc[m]);
      }
    }
    asm volatile("s_waitcnt lgkmcnt(0)" ::: "memory");  // my reads done
    __builtin_amdgcn_sched_barrier(0);
    __builtin_amdgcn_s_barrier();
    stage_slice(kt + 2, cur);  // overwrite just-computed buffer (kt+2 <= 17)
    cur ^= 1;
  }

  // ---- Phase 2: masked softmax (overlaps V slices 16,17 in flight) -------
  const int qr = t0w + l15;
  float mx = NEG_BIG;
#pragma unroll
  for (int m = 0; m < 32; m++) {
    if (m <= mmax) {
#pragma unroll
      for (int r = 0; r < 4; r++) {
        const int kv = kv0 + m * 16 + quad * 4 + r;
        const float vvv = (kv <= qr) ? Sacc[m][r] : NEG_BIG;
        Sacc[m][r] = vvv;
        mx = fmaxf(mx, vvv);
      }
    }
  }
  mx = fmaxf(mx, __shfl_xor(mx, 16));
  mx = fmaxf(mx, __shfl_xor(mx, 32));  // finite: kv0 <= qr always

  float lrow = 0.0f;
  bf16x4 pb[32];
#pragma unroll
  for (int m = 0; m < 32; m++) {
    bf16x4 pv = {};
    if (m <= mmax) {
#pragma unroll
      for (int r = 0; r < 4; r++) {
        const float p = __expf((Sacc[m][r] - mx) * scale);  // masked -> 0
        pv[r] = (bf16_t)p;
        lrow += p;
      }
    }
    pb[m] = pv;
  }
  lrow += __shfl_xor(lrow, 16);
  lrow += __shfl_xor(lrow, 32);

  if (quad == 0)
    stats[((size_t)w * 4 + b) * 64 + wid * 16 + l15] =
        make_float2(mx * scale, lrow);

  // ---- Phase 3: O = P.V, both 256-d halves, unrolled kvt (rule #20) ------
  const int l64 = l15 * 64;
  const int qh = quad >> 1;
  const int ql = (quad & 1) * 4;
  const int s7 = l15 & 7;

#pragma unroll
  for (int dh = 0; dh < 2; dh++) {
    f32x4 Oacc[16];
#pragma unroll
    for (int dt = 0; dt < 16; dt++) Oacc[dt] = f32x4{0.f, 0.f, 0.f, 0.f};

#pragma unroll
    for (int kvt = 0; kvt < 8; kvt++) {
      if (kvt < NV) {  // block-uniform
        const int u = 16 + dh * NV + kvt;
        if (u < NSLICE - 1)
          asm volatile("s_waitcnt vmcnt(8)" ::: "memory");
        else
          asm volatile("s_waitcnt vmcnt(0)" ::: "memory");
        __builtin_amdgcn_sched_barrier(0);
        __builtin_amdgcn_s_barrier();
        if (kvt <= kvtmax) {  // wave-uniform
          const bf16_t* sb = &SB[cur][0];
#pragma unroll
          for (int dt = 0; dt < 16; dt++) {
#pragma unroll
            for (int gg = 0; gg < 4; gg++) {
              const bf16x4 vf = *(const bf16x4*)(
                  sb + dt * 1024 + l64 + (((gg * 2 + qh) ^ s7) << 3) + ql);
              Oacc[dt] = mfma16(pb[kvt * 4 + gg], vf, Oacc[dt]);
            }
          }
        }
        // epilogue on last live kvt: coalesced native-layout stores
        if (kvt == NV - 1) {
          bf16_t* pbase =
              partO + (size_t)obid * 32768 + dh * 16384 + wid * 4096;
#pragma unroll
          for (int dt = 0; dt < 16; dt++) {
            bf16x4 ov;
#pragma unroll
            for (int r = 0; r < 4; r++) ov[r] = (bf16_t)Oacc[dt][r];
            *(bf16x4*)(pbase + dt * 256 + l15 * 16 + quad * 4) = ov;
          }
        }
        asm volatile("s_waitcnt lgkmcnt(0)" ::: "memory");
        __builtin_amdgcn_sched_barrier(0);
        __builtin_amdgcn_s_barrier();
        if (u + 2 < NSLICE) stage_slice(u + 2, cur);
        cur ^= 1;
      }
    }
  }
}

// ---------------------------------------------------------------------------
// Stage 2: combine chunk partials per (b, s64, dh). Grid 512 (dh-split).
// Reads partO native layout coalesced, normalizes in registers, transposes
// through a row-XOR-swizzled 32 KB LDS bounce, writes coalesced bf16x8 rows.
// ---------------------------------------------------------------------------
__global__ __launch_bounds__(256) void attn_combine_kernel(
    const bf16_t* __restrict__ partO, const float2* __restrict__ stats,
    bf16_t* __restrict__ o) {
  const int b = blockIdx.x & 3;
  const int s = (blockIdx.x >> 2) & 63;
  const int dh = blockIdx.x >> 8;
  const int g = s >> 3;
  const int nc = g + 1;
  const int w0 = 4 * g * (g + 1) + (s & 7) * (g + 1);

  __shared__ float wgt[8][64];
  __shared__ float linv[64];
  __shared__ bf16_t TB[64 * 256];  // 32 KB transpose bounce

  const int tid = threadIdx.x;
  if (tid < 64) {
    float mc[8], lc[8];
    float M = NEG_BIG;
    for (int cc = 0; cc < nc; cc++) {
      const float2 ml = stats[((size_t)(w0 + cc) * 4 + b) * 64 + tid];
      mc[cc] = ml.x;
      lc[cc] = ml.y;
      M = fmaxf(M, ml.x);
    }
    float L = 0.0f;
    for (int cc = 0; cc < nc; cc++) {
      const float wv = __expf(mc[cc] - M);
      wgt[cc][tid] = wv;
      L += wv * lc[cc];
    }
    linv[tid] = (L > 0.0f) ? 1.0f / L : 0.0f;
  }
  __syncthreads();

  // thread decode matching native layout: q-rows q0..q0+3, d = dt*16 + l15
  const int quad = tid & 3;
  const int l15 = (tid >> 2) & 15;
  const int wid = tid >> 6;
  const int q0 = wid * 16 + quad * 4;
  const f32x4 li4 = *(const f32x4*)(&linv[q0]);

  f32x4 acc4[16] = {};
  for (int cc = 0; cc < nc; cc++) {
    const bf16_t* pp = partO + (size_t)(((w0 + cc) << 2) | b) * 32768 +
                       dh * 16384 + wid * 4096 + l15 * 16 + quad * 4;
    const f32x4 wv4 = *(const f32x4*)(&wgt[cc][q0]);
#pragma unroll
    for (int dt = 0; dt < 16; dt++) {
      const bf16x4 p = *(const bf16x4*)(pp + dt * 256);
#pragma unroll
      for (int e = 0; e < 4; e++) acc4[dt][e] += wv4[e] * (float)p[e];
    }
  }
  // normalize + swizzled bounce write ([64 q][256 d] bf16, row XOR)
#pragma unroll
  for (int dt = 0; dt < 16; dt++) {
    const int d2 = (dt * 16 + l15) * 2;
#pragma unroll
    for (int r = 0; r < 4; r++) {
      const int qq = q0 + r;
      *(bf16_t*)((char*)TB + qq * 512 + (d2 ^ ((qq & 7) << 4))) =
          (bf16_t)(acc4[dt][r] * li4[r]);
    }
  }
  __syncthreads();
  // coalesced read + store
  const int row = tid >> 2;
  const int quarter = tid & 3;
  bf16_t* orow =
      o + ((size_t)(b * 4096 + s * 64 + row)) * 512 + dh * 256 + quarter * 64;
#pragma unroll
  for (int j = 0; j < 8; j++) {
    const int byte = row * 512 + ((quarter * 128 + j * 16) ^ ((row & 7) << 4));
    *(bf16x8*)(orow + j * 8) = *(const bf16x8*)((const char*)TB + byte);
  }
}

// ---------------------------------------------------------------------------
extern "C" void kernel_launch(void* const* d_in, const int* in_sizes, int n_in,
                              void* d_out, int out_size, void* d_ws, size_t ws_size,
                              hipStream_t stream) {
  const float* x_f = (const float*)d_in[0];   // [4,4096,512] fp32
  const float* wq_f = (const float*)d_in[1];  // [1536,512]   fp32
  const float* wp_f = (const float*)d_in[2];  // [512,512]    fp32
  float* out = (float*)d_out;                 // [4,4096,512] fp32

  // ws (bf16 unless noted): xb | wqb | wpb | q | k | vT | partO | stats
  bf16_t* xb = (bf16_t*)d_ws;                      // 16 MB (attn output)
  bf16_t* wqb = xb + (size_t)16384 * 512;          // 1.5 MB
  bf16_t* wpb = wqb + (size_t)1536 * 512;          // 0.5 MB
  bf16_t* q = wpb + (size_t)512 * 512;             // 16 MB
  bf16_t* kk = q + (size_t)16384 * 512;            // 16 MB
  bf16_t* vT = kk + (size_t)16384 * 512;           // 16 MB
  bf16_t* partO = vT + (size_t)16384 * 512;        // 1152*32768*2 = 75.5 MB
  float2* stats = (float2*)(partO + (size_t)1152 * 32768);  // 0.6 MB

  // 0) convert fp32 inputs -> bf16 (single launch)
  cvt3_kernel<<<9216, 256, 0, stream>>>(x_f, wq_f, wp_f, xb, wqb, wpb);

  // 1) qkv = x @ Wqkv^T ; v stored transposed (A-panel XCD locality)
  gemm_bt_kernel<0><<<128 * 12, 256, 0, stream>>>(xb, wqb, q, kk, vT, nullptr);
  // 2a) attention partials (R9 body + XCD pinning + longest-first order)
  attn_part_kernel<<<1152, 256, 0, stream>>>(q, kk, vT, partO, stats);
  // 2b) combine partials -> xb (dh-split grid)
  attn_combine_kernel<<<512, 256, 0, stream>>>(partO, stats, xb);
  // 3) y = attn @ Wproj^T -> fp32 d_out (A-panel XCD locality)
  gemm_bt_kernel<1><<<128 * 4, 256, 0, stream>>>(xb, wpb, nullptr, nullptr, nullptr, out);
}